// Round 7
// baseline (508.018 us; speedup 1.0000x reference)
//
#include <hip/hip_runtime.h>
#include <math.h>

#define D_   256
#define H_   8
#define L_   2
#define FF_  1024
#define S_   512
#define B_   32
#define M_   4096
#define NC_  10
#define ROWS (B_*S_)   // 16384

typedef __attribute__((ext_vector_type(8))) short bf16x8;
typedef __attribute__((ext_vector_type(4))) float f32x4;

__device__ __forceinline__ float wave_sum(float v) {
#pragma unroll
  for (int off = 1; off < 64; off <<= 1) v += __shfl_xor(v, off, 64);
  return v;
}

__device__ __forceinline__ unsigned short bf16_rne(float x) {
  unsigned int b = __float_as_uint(x);
  return (unsigned short)((b + 0x7FFFu + ((b >> 16) & 1u)) >> 16);
}
__device__ __forceinline__ float bf16_f(unsigned short h) {
  return __uint_as_float(((unsigned int)h) << 16);
}
__device__ __forceinline__ unsigned int cvt_pk_bf16(float a, float b) {
  unsigned int r;
  asm volatile("v_cvt_pk_bf16_f32 %0, %1, %2" : "=v"(r) : "v"(a), "v"(b));
  return r;
}

// convert float4 -> hi/lo bf16 quads, store 8B each into padded LDS tiles
__device__ __forceinline__ void cvt_store(unsigned short* Hq, unsigned short* Lq,
                                          int off, float4 v) {
  float f[4] = {v.x, v.y, v.z, v.w};
  unsigned short h[4], l[4];
#pragma unroll
  for (int i = 0; i < 4; i++) {
    h[i] = bf16_rne(f[i]);
    l[i] = bf16_rne(f[i] - bf16_f(h[i]));
  }
  uint2 hp, lp;
  hp.x = (unsigned int)h[0] | ((unsigned int)h[1] << 16);
  hp.y = (unsigned int)h[2] | ((unsigned int)h[3] << 16);
  lp.x = (unsigned int)l[0] | ((unsigned int)l[1] << 16);
  lp.y = (unsigned int)l[2] | ((unsigned int)l[3] << 16);
  *(uint2*)&Hq[off] = hp;
  *(uint2*)&Lq[off] = lp;
}

// ---------------- embedding ----------------
__global__ __launch_bounds__(256) void emb_kernel(const int* __restrict__ ids,
                                                  const float* __restrict__ tok,
                                                  const float* __restrict__ pos,
                                                  float* __restrict__ x) {
  const int row  = blockIdx.x * 4 + (threadIdx.x >> 6);
  const int lane = threadIdx.x & 63;
  const int id = ids[row];
  const int s  = row & (S_ - 1);
  const float4 t = *(const float4*)(tok + (size_t)id * D_ + lane * 4);
  const float4 p = *(const float4*)(pos + (size_t)s  * D_ + lane * 4);
  float4 r; r.x = t.x + p.x; r.y = t.y + p.y; r.z = t.z + p.z; r.w = t.w + p.w;
  *(float4*)(x + (size_t)row * D_ + lane * 4) = r;
}

// ---- split-bf16 MFMA GEMM: C[M,N] = A[M,K]*W[N,K]^T + bias (+ReLU) --------
#define LPITCH 40
template<int BM, int RELU>
__global__ __launch_bounds__(512, 4) void gemm_mfma(const float* __restrict__ A,
                                                    const float* __restrict__ Bm,
                                                    const float* __restrict__ bias,
                                                    float* __restrict__ C,
                                                    int M, int N, int K) {
  constexpr int WGM = BM / 64;
  constexpr int WGN = 8 / WGM;
  constexpr int WN  = 128 / WGN;
  constexpr int FN  = WN / 16;
  __shared__ unsigned short Ah[BM * LPITCH];
  __shared__ unsigned short Al[BM * LPITCH];
  __shared__ unsigned short Bh[128 * LPITCH];
  __shared__ unsigned short Bl[128 * LPITCH];

  const int tid  = threadIdx.x;
  const int lane = tid & 63;
  const int wid  = tid >> 6;
  const int wm = wid / WGN, wn = wid % WGN;
  const int m0 = blockIdx.y * BM, n0 = blockIdx.x * 128;
  const int lrow  = lane & 15;
  const int khalf = (lane >> 4) * 8;

  f32x4 acc[4][FN];
#pragma unroll
  for (int i = 0; i < 4; i++)
#pragma unroll
    for (int j = 0; j < FN; j++) acc[i][j] = (f32x4){0.f, 0.f, 0.f, 0.f};

  const float* Abase = A + (size_t)m0 * K;
  const float* Bbase = Bm + (size_t)n0 * K;

  for (int k0 = 0; k0 < K; k0 += 32) {
    __syncthreads();
#pragma unroll
    for (int j = 0; j < BM / 64; j++) {
      const int idx = tid + j * 512;
      const int row = idx >> 3, kq = (idx & 7) << 2;
      const float4 v = *(const float4*)(Abase + (size_t)row * K + k0 + kq);
      cvt_store(Ah, Al, row * LPITCH + kq, v);
    }
#pragma unroll
    for (int j = 0; j < 2; j++) {
      const int idx = tid + j * 512;
      const int row = idx >> 3, kq = (idx & 7) << 2;
      const float4 v = *(const float4*)(Bbase + (size_t)row * K + k0 + kq);
      cvt_store(Bh, Bl, row * LPITCH + kq, v);
    }
    __syncthreads();

    bf16x8 ah[4], al[4], bh[FN], bl[FN];
#pragma unroll
    for (int fm = 0; fm < 4; fm++) {
      const int r = (wm * 64 + fm * 16 + lrow) * LPITCH + khalf;
      ah[fm] = *(const bf16x8*)&Ah[r];
      al[fm] = *(const bf16x8*)&Al[r];
    }
#pragma unroll
    for (int fn = 0; fn < FN; fn++) {
      const int r = (wn * WN + fn * 16 + lrow) * LPITCH + khalf;
      bh[fn] = *(const bf16x8*)&Bh[r];
      bl[fn] = *(const bf16x8*)&Bl[r];
    }
#pragma unroll
    for (int fm = 0; fm < 4; fm++)
#pragma unroll
      for (int fn = 0; fn < FN; fn++) {
        acc[fm][fn] = __builtin_amdgcn_mfma_f32_16x16x32_bf16(ah[fm], bh[fn], acc[fm][fn], 0, 0, 0);
        acc[fm][fn] = __builtin_amdgcn_mfma_f32_16x16x32_bf16(ah[fm], bl[fn], acc[fm][fn], 0, 0, 0);
        acc[fm][fn] = __builtin_amdgcn_mfma_f32_16x16x32_bf16(al[fm], bh[fn], acc[fm][fn], 0, 0, 0);
      }
  }

#pragma unroll
  for (int fm = 0; fm < 4; fm++)
#pragma unroll
    for (int fn = 0; fn < FN; fn++) {
      const int mrow = m0 + wm * 64 + fm * 16 + (lane >> 4) * 4;
      const int ncol = n0 + wn * WN + fn * 16 + (lane & 15);
      const float bi = bias[ncol];
#pragma unroll
      for (int r = 0; r < 4; r++) {
        float v = acc[fm][fn][r] + bi;
        if (RELU) v = fmaxf(v, 0.f);
        C[(size_t)(mrow + r) * N + ncol] = v;
      }
    }
}

// ---------------- MFMA attention -------------------------------------------
#define KPITCH 40   // u16 per K row   (80B, 16B aligned, 2-way-free b128 reads)
#define VPITCH 520  // u16 per Vt row  (1040B, 16B aligned, 2-way-free)
__global__ __launch_bounds__(512, 2) void attn_mfma(const float* __restrict__ qkv,
                                                    float* __restrict__ o) {
  __shared__ unsigned short Kh[512 * KPITCH];
  __shared__ unsigned short Kl[512 * KPITCH];
  __shared__ unsigned short Vth[32 * VPITCH];
  __shared__ unsigned short Vtl[32 * VPITCH];

  const int bh = blockIdx.x;
  const int b = bh >> 3, h = bh & 7;
  const int tid = threadIdx.x;
  const int lane = tid & 63;
  const int wv = tid >> 6;
  const float* base = qkv + (size_t)b * (S_ * 768) + h * 32;

  // ---- stage: threads 0..255 -> V^T (2 rows each), 256..511 -> K (2 rows) --
  if (tid < 256) {
    float v0[32], v1[32];
    const float* p0 = base + (size_t)(2 * tid) * 768 + 512;
    const float* p1 = p0 + 768;
#pragma unroll
    for (int i = 0; i < 8; i++) {
      *(float4*)&v0[i * 4] = *(const float4*)(p0 + i * 4);
      *(float4*)&v1[i * 4] = *(const float4*)(p1 + i * 4);
    }
#pragma unroll
    for (int d = 0; d < 32; d++) {
      const unsigned short h0 = bf16_rne(v0[d]), h1 = bf16_rne(v1[d]);
      const unsigned short l0 = bf16_rne(v0[d] - bf16_f(h0));
      const unsigned short l1 = bf16_rne(v1[d] - bf16_f(h1));
      *(unsigned int*)&Vth[d * VPITCH + 2 * tid] = (unsigned int)h0 | ((unsigned int)h1 << 16);
      *(unsigned int*)&Vtl[d * VPITCH + 2 * tid] = (unsigned int)l0 | ((unsigned int)l1 << 16);
    }
  } else {
    const int t = tid - 256;
#pragma unroll
    for (int rr = 0; rr < 2; rr++) {
      const int k = 2 * t + rr;
      const float* p = base + (size_t)k * 768 + 256;
      float kv[32];
#pragma unroll
      for (int i = 0; i < 8; i++) *(float4*)&kv[i * 4] = *(const float4*)(p + i * 4);
#pragma unroll
      for (int d = 0; d < 32; d += 2) {
        const unsigned short h0 = bf16_rne(kv[d]), h1 = bf16_rne(kv[d + 1]);
        const unsigned short l0 = bf16_rne(kv[d] - bf16_f(h0));
        const unsigned short l1 = bf16_rne(kv[d + 1] - bf16_f(h1));
        *(unsigned int*)&Kh[k * KPITCH + d] = (unsigned int)h0 | ((unsigned int)h1 << 16);
        *(unsigned int*)&Kl[k * KPITCH + d] = (unsigned int)l0 | ((unsigned int)l1 << 16);
      }
    }
  }

  // ---- per-wave Q B-fragments (scale folded in), kept in registers --------
  const int q0 = wv * 64;
  bf16x8 qh[4], ql[4];
#pragma unroll
  for (int f = 0; f < 4; f++) {
    const float* qp = base + (size_t)(q0 + f * 16 + (lane & 15)) * 768 + ((lane >> 4) * 8);
    float qq[8];
    *(float4*)&qq[0] = *(const float4*)qp;
    *(float4*)&qq[4] = *(const float4*)(qp + 4);
    bf16x8 vh, vl;
#pragma unroll
    for (int j = 0; j < 8; j++) {
      const float sv = qq[j] * 0.17677669529663687f;
      const unsigned short hh = bf16_rne(sv);
      vh[j] = (short)hh;
      vl[j] = (short)bf16_rne(sv - bf16_f(hh));
    }
    qh[f] = vh; ql[f] = vl;
  }

  __syncthreads();

  f32x4 oacc[2][4];   // [d-frag][q-frag], O^T: row=d, col=q
#pragma unroll
  for (int i = 0; i < 2; i++)
#pragma unroll
    for (int j = 0; j < 4; j++) oacc[i][j] = (f32x4){0.f, 0.f, 0.f, 0.f};
  float lacc[4] = {0.f, 0.f, 0.f, 0.f};

  const int idx01 = (lane & 15) + ((lane & 16) << 1);  // +32 if bit4 set
  const int idx23 = idx01 + 16;
  const bool hiSel = (lane & 32) != 0;

  for (int kt = 0; kt < S_; kt += 32) {
    bf16x8 kah[2], kal[2];
#pragma unroll
    for (int u = 0; u < 2; u++) {
      const int off = (kt + u * 16 + (lane & 15)) * KPITCH + ((lane >> 4) * 8);
      kah[u] = *(const bf16x8*)&Kh[off];
      kal[u] = *(const bf16x8*)&Kl[off];
    }
    bf16x8 vah[2], val[2];
#pragma unroll
    for (int df = 0; df < 2; df++) {
      const int off = (df * 16 + (lane & 15)) * VPITCH + kt + ((lane >> 4) * 8);
      vah[df] = *(const bf16x8*)&Vth[off];
      val[df] = *(const bf16x8*)&Vtl[off];
    }
    f32x4 s[2][4];
#pragma unroll
    for (int u = 0; u < 2; u++)
#pragma unroll
      for (int f = 0; f < 4; f++) {
        f32x4 a = (f32x4){0.f, 0.f, 0.f, 0.f};
        a = __builtin_amdgcn_mfma_f32_16x16x32_bf16(kal[u], qh[f], a, 0, 0, 0);
        a = __builtin_amdgcn_mfma_f32_16x16x32_bf16(kah[u], ql[f], a, 0, 0, 0);
        a = __builtin_amdgcn_mfma_f32_16x16x32_bf16(kah[u], qh[f], a, 0, 0, 0);
        s[u][f] = a;
      }
    unsigned int ah[2][4][2], alw[2][4][2];
#pragma unroll
    for (int u = 0; u < 2; u++)
#pragma unroll
      for (int f = 0; f < 4; f++) {
        const float p0 = __expf(s[u][f][0]);
        const float p1 = __expf(s[u][f][1]);
        const float p2 = __expf(s[u][f][2]);
        const float p3 = __expf(s[u][f][3]);
        lacc[f] += (p0 + p1) + (p2 + p3);
        const unsigned int h01 = cvt_pk_bf16(p0, p1);
        const unsigned int h23 = cvt_pk_bf16(p2, p3);
        const float r0 = p0 - __uint_as_float(h01 << 16);
        const float r1 = p1 - __uint_as_float(h01 & 0xffff0000u);
        const float r2 = p2 - __uint_as_float(h23 << 16);
        const float r3 = p3 - __uint_as_float(h23 & 0xffff0000u);
        ah[u][f][0] = h01; ah[u][f][1] = h23;
        alw[u][f][0] = cvt_pk_bf16(r0, r1);
        alw[u][f][1] = cvt_pk_bf16(r2, r3);
      }
#pragma unroll
    for (int f = 0; f < 4; f++) {
      union { unsigned int w[4]; bf16x8 v; } ph, pl;
      {
        const unsigned int t0 = (unsigned int)__shfl((int)ah[0][f][0], idx01, 64);
        const unsigned int t1 = (unsigned int)__shfl((int)ah[1][f][0], idx01, 64);
        ph.w[0] = hiSel ? t1 : t0;
      }
      {
        const unsigned int t0 = (unsigned int)__shfl((int)ah[0][f][1], idx01, 64);
        const unsigned int t1 = (unsigned int)__shfl((int)ah[1][f][1], idx01, 64);
        ph.w[1] = hiSel ? t1 : t0;
      }
      {
        const unsigned int t0 = (unsigned int)__shfl((int)ah[0][f][0], idx23, 64);
        const unsigned int t1 = (unsigned int)__shfl((int)ah[1][f][0], idx23, 64);
        ph.w[2] = hiSel ? t1 : t0;
      }
      {
        const unsigned int t0 = (unsigned int)__shfl((int)ah[0][f][1], idx23, 64);
        const unsigned int t1 = (unsigned int)__shfl((int)ah[1][f][1], idx23, 64);
        ph.w[3] = hiSel ? t1 : t0;
      }
      {
        const unsigned int t0 = (unsigned int)__shfl((int)alw[0][f][0], idx01, 64);
        const unsigned int t1 = (unsigned int)__shfl((int)alw[1][f][0], idx01, 64);
        pl.w[0] = hiSel ? t1 : t0;
      }
      {
        const unsigned int t0 = (unsigned int)__shfl((int)alw[0][f][1], idx01, 64);
        const unsigned int t1 = (unsigned int)__shfl((int)alw[1][f][1], idx01, 64);
        pl.w[1] = hiSel ? t1 : t0;
      }
      {
        const unsigned int t0 = (unsigned int)__shfl((int)alw[0][f][0], idx23, 64);
        const unsigned int t1 = (unsigned int)__shfl((int)alw[1][f][0], idx23, 64);
        pl.w[2] = hiSel ? t1 : t0;
      }
      {
        const unsigned int t0 = (unsigned int)__shfl((int)alw[0][f][1], idx23, 64);
        const unsigned int t1 = (unsigned int)__shfl((int)alw[1][f][1], idx23, 64);
        pl.w[3] = hiSel ? t1 : t0;
      }
#pragma unroll
      for (int df = 0; df < 2; df++) {
        oacc[df][f] = __builtin_amdgcn_mfma_f32_16x16x32_bf16(val[df], ph.v, oacc[df][f], 0, 0, 0);
        oacc[df][f] = __builtin_amdgcn_mfma_f32_16x16x32_bf16(vah[df], pl.v, oacc[df][f], 0, 0, 0);
        oacc[df][f] = __builtin_amdgcn_mfma_f32_16x16x32_bf16(vah[df], ph.v, oacc[df][f], 0, 0, 0);
      }
    }
  }

#pragma unroll
  for (int f = 0; f < 4; f++) {
    lacc[f] += __shfl_xor(lacc[f], 16, 64);
    lacc[f] += __shfl_xor(lacc[f], 32, 64);
  }
#pragma unroll
  for (int f = 0; f < 4; f++) {
    const float inv = 1.f / lacc[f];
    const int q = q0 + f * 16 + (lane & 15);
    float* op = o + (size_t)(b * S_ + q) * D_ + h * 32;
#pragma unroll
    for (int df = 0; df < 2; df++) {
      const int dbase = df * 16 + (lane >> 4) * 4;
#pragma unroll
      for (int r = 0; r < 4; r++)
        op[dbase + r] = oacc[df][f][r] * inv;
    }
  }
}

// ---------------- fused residual + layernorm (one wave per row) -------------
__global__ __launch_bounds__(256) void add_ln(const float* __restrict__ x,
                                              const float* __restrict__ y,
                                              const float* __restrict__ g,
                                              const float* __restrict__ bta,
                                              float* __restrict__ out) {
  const int row  = blockIdx.x * 4 + (threadIdx.x >> 6);
  const int lane = threadIdx.x & 63;
  const size_t base = (size_t)row * D_ + lane * 4;
  const float4 xv = *(const float4*)(x + base);
  const float4 yv = *(const float4*)(y + base);
  float v[4] = {xv.x + yv.x, xv.y + yv.y, xv.z + yv.z, xv.w + yv.w};
  float s = v[0] + v[1] + v[2] + v[3];
  s = wave_sum(s);
  const float mean = s * (1.f / 256.f);
  float d[4] = {v[0] - mean, v[1] - mean, v[2] - mean, v[3] - mean};
  float sq = d[0] * d[0] + d[1] * d[1] + d[2] * d[2] + d[3] * d[3];
  sq = wave_sum(sq);
  const float inv = 1.f / sqrtf(sq * (1.f / 256.f) + 1e-5f);
  const float4 gv = *(const float4*)(g + lane * 4);
  const float4 bv = *(const float4*)(bta + lane * 4);
  float4 r;
  r.x = d[0] * inv * gv.x + bv.x; r.y = d[1] * inv * gv.y + bv.y;
  r.z = d[2] * inv * gv.z + bv.z; r.w = d[3] * inv * gv.w + bv.w;
  *(float4*)(out + base) = r;
}

// ---------------- gate logit -> mask ----------------------------------------
__global__ __launch_bounds__(256) void gate_mask(const float* __restrict__ t,
                                                 const float* __restrict__ Wg2,
                                                 const float* __restrict__ bg2,
                                                 int* __restrict__ mask) {
  const int row  = blockIdx.x * 4 + (threadIdx.x >> 6);
  const int lane = threadIdx.x & 63;
  const float4 tv = *(const float4*)(t + (size_t)row * D_ + lane * 4);
  const float4 wv = *(const float4*)(Wg2 + lane * 4);
  float s = tv.x * wv.x + tv.y * wv.y + tv.z * wv.z + tv.w * wv.w;
  s = wave_sum(s);
  if (lane == 0) mask[row] = (s + bg2[0]) > 0.f ? 1 : 0;
}

// -------- parallel prefix-scan over 16384 masks (sequential semantics) ------
__global__ __launch_bounds__(256) void scan_kernel(const int* __restrict__ mask,
                                                   int* __restrict__ slots,
                                                   int* __restrict__ countp) {
  __shared__ int wtot[4];
  const int tid = threadIdx.x;
  const int lane = tid & 63, wid = tid >> 6;
  const int base = tid * 64;
  int s = 0;
#pragma unroll 8
  for (int i = 0; i < 64; i++) s += mask[base + i];
  // wave-inclusive scan
  int inc = s;
#pragma unroll
  for (int off = 1; off < 64; off <<= 1) {
    const int t = __shfl_up(inc, off, 64);
    if (lane >= off) inc += t;
  }
  if (lane == 63) wtot[wid] = inc;
  __syncthreads();
  int woff = 0;
#pragma unroll
  for (int w = 0; w < 4; w++) woff += (w < wid) ? wtot[w] : 0;
  const int total = wtot[0] + wtot[1] + wtot[2] + wtot[3];
  if (tid == 0) countp[0] = total < M_ ? total : M_;
  int run = woff + inc - s;  // exclusive prefix for this thread's chunk
  for (int i = 0; i < 64; i++) {
    const int r = base + i;
    const int mk = mask[r];
    slots[r] = (mk && run < M_) ? run : -1;
    run += mk;
  }
}

// ---------------- scatter selected rows into memory -------------------------
__global__ __launch_bounds__(256) void scatter_kernel(const float* __restrict__ h,
                                                      const int* __restrict__ slots,
                                                      float* __restrict__ mem) {
  const int row  = blockIdx.x * 4 + (threadIdx.x >> 6);
  const int lane = threadIdx.x & 63;
  const int sl = slots[row];
  if (sl >= 0)
    *(float4*)(mem + (size_t)sl * D_ + lane * 4) =
        *(const float4*)(h + (size_t)row * D_ + lane * 4);
}

// ---------------- query norms (one wave per batch row) ----------------------
__global__ __launch_bounds__(256) void qnorm_kernel(const float* __restrict__ h,
                                                    float* __restrict__ qden) {
  const int b    = blockIdx.x * 4 + (threadIdx.x >> 6);
  const int lane = threadIdx.x & 63;
  const float4 c = *(const float4*)(h + (size_t)b * S_ * D_ + lane * 4);
  float sq = c.x * c.x + c.y * c.y + c.z * c.z + c.w * c.w;
  sq = wave_sum(sq);
  if (lane == 0) qden[b] = sqrtf(sq) + 1e-8f;
}

// ------- sims[b][r] for all 32 b: one wave per memory row r -----------------
__global__ __launch_bounds__(256) void sims_kernel(const float* __restrict__ h,
                                                   const float* __restrict__ mem,
                                                   const float* __restrict__ qden,
                                                   const int* __restrict__ countp,
                                                   float* __restrict__ sims) {
  __shared__ float cls[B_ * D_];
  __shared__ float qd[B_];
  const int tid = threadIdx.x;
  const int lane = tid & 63, wid = tid >> 6;
  for (int i = tid; i < B_ * D_ / 4; i += 256) {
    const int flat = i * 4;
    const int b = flat >> 8, d = flat & 255;
    *(float4*)&cls[flat] = *(const float4*)(h + (size_t)b * S_ * D_ + d);
  }
  if (tid < B_) qd[tid] = qden[tid];
  __syncthreads();
  const int count = countp[0];
  const int r = blockIdx.x * 4 + wid;
  const float4 m4 = *(const float4*)(mem + (size_t)r * D_ + lane * 4);
  float sq = m4.x * m4.x + m4.y * m4.y + m4.z * m4.z + m4.w * m4.w;
  sq = wave_sum(sq);
  const float rn = sqrtf(sq) + 1e-8f;
  if (r < count) {
    for (int b = 0; b < B_; b++) {
      const float4 c4 = *(const float4*)&cls[b * D_ + lane * 4];
      float dt = m4.x * c4.x + m4.y * c4.y + m4.z * c4.z + m4.w * c4.w;
      dt = wave_sum(dt);
      if (lane == 0) sims[b * M_ + r] = dt / (qd[b] * rn);
    }
  } else if (lane == 0) {
    for (int b = 0; b < B_; b++) sims[b * M_ + r] = -1e9f;
  }
}

// ---------------- per-batch: top-4 (wave-parallel argmax), mix, classifier --
__global__ __launch_bounds__(256) void topk_mix(const float* __restrict__ h,
                                                const float* __restrict__ mem,
                                                const float* __restrict__ simsg,
                                                const int* __restrict__ countp,
                                                const float* __restrict__ Wc,
                                                const float* __restrict__ bc,
                                                float* __restrict__ out) {
  __shared__ float sims[M_];
  __shared__ float cls[D_];
  __shared__ float wv4[4];
  __shared__ int   wi4[4];
  __shared__ float aug[D_];
  __shared__ float tv[4];
  __shared__ int   tix[4];

  const int b = blockIdx.x, tid = threadIdx.x;
  const int lane = tid & 63, wid = tid >> 6;
  const int count = countp[0];

  for (int i = tid; i < M_; i += 256) sims[i] = simsg[b * M_ + i];
  cls[tid] = h[(size_t)b * S_ * D_ + tid];
  __syncthreads();

  for (int k = 0; k < 4; k++) {
    float bv = -INFINITY; int bi = 1 << 30;
#pragma unroll
    for (int rr = 0; rr < M_ / 256; rr++) {
      const int r = tid + rr * 256;
      const float v = sims[r];
      if (v > bv || (v == bv && r < bi)) { bv = v; bi = r; }
    }
    // wave argmax butterfly (tie: lower index)
#pragma unroll
    for (int off = 1; off < 64; off <<= 1) {
      const float ov = __shfl_xor(bv, off, 64);
      const int   oi = __shfl_xor(bi, off, 64);
      if (ov > bv || (ov == bv && oi < bi)) { bv = ov; bi = oi; }
    }
    if (lane == 0) { wv4[wid] = bv; wi4[wid] = bi; }
    __syncthreads();
    if (tid == 0) {
      float bb = wv4[0]; int bbi = wi4[0];
#pragma unroll
      for (int i = 1; i < 4; i++)
        if (wv4[i] > bb || (wv4[i] == bb && wi4[i] < bbi)) { bb = wv4[i]; bbi = wi4[i]; }
      tv[k] = bb; tix[k] = bbi; sims[bbi] = -INFINITY;
    }
    __syncthreads();
  }

  float w[4];
  {
    const float mx = tv[0];
    float ws = 0.f;
#pragma unroll
    for (int k = 0; k < 4; k++) { w[k] = expf(tv[k] - mx); ws += w[k]; }
    const float inv = 1.f / ws;
#pragma unroll
    for (int k = 0; k < 4; k++) w[k] *= inv;
  }

  {
    float mv = 0.f;
    if (count > 0) {
#pragma unroll
      for (int k = 0; k < 4; k++) mv = fmaf(w[k], mem[(size_t)tix[k] * D_ + tid], mv);
    }
    aug[tid] = cls[tid] + mv;
  }
  __syncthreads();

  const float4 a4 = *(const float4*)&aug[lane * 4];
  for (int c = wid; c < NC_; c += 4) {
    const float4 wc = *(const float4*)(Wc + (size_t)c * D_ + lane * 4);
    float dt = a4.x * wc.x + a4.y * wc.y + a4.z * wc.z + a4.w * wc.w;
    dt = wave_sum(dt);
    if (lane == 0) out[b * NC_ + c] = dt + bc[c];
  }
}

// ---------------- launcher ---------------------------------------------------
extern "C" void kernel_launch(void* const* d_in, const int* in_sizes, int n_in,
                              void* d_out, int out_size, void* d_ws, size_t ws_size,
                              hipStream_t stream) {
  const int*   ids  = (const int*)d_in[0];
  const float* tok  = (const float*)d_in[1];
  const float* pos  = (const float*)d_in[2];
  const float* Wqkv = (const float*)d_in[3];
  const float* bqkv = (const float*)d_in[4];
  const float* Wo   = (const float*)d_in[5];
  const float* bo   = (const float*)d_in[6];
  const float* ln1g = (const float*)d_in[7];
  const float* ln1b = (const float*)d_in[8];
  const float* W1   = (const float*)d_in[9];
  const float* b1   = (const float*)d_in[10];
  const float* W2   = (const float*)d_in[11];
  const float* b2   = (const float*)d_in[12];
  const float* ln2g = (const float*)d_in[13];
  const float* ln2b = (const float*)d_in[14];
  const float* Wg1  = (const float*)d_in[15];
  const float* bg1  = (const float*)d_in[16];
  const float* Wg2  = (const float*)d_in[17];
  const float* bg2  = (const float*)d_in[18];
  const float* Wc   = (const float*)d_in[19];
  const float* bc   = (const float*)d_in[20];
  float* out = (float*)d_out;

  float* xA   = (float*)d_ws;
  float* xB   = xA  + (size_t)ROWS * D_;
  float* ob   = xB  + (size_t)ROWS * D_;
  float* pb   = ob  + (size_t)ROWS * D_;
  float* big  = pb  + (size_t)ROWS * D_;
  float* mem  = big + (size_t)ROWS * FF_;
  float* qden = mem + (size_t)M_ * D_;
  float* sims = qden + 64;
  int*   mask = (int*)(sims + (size_t)B_ * M_);
  int*   slots = mask + ROWS;
  int*   cnt   = slots + ROWS;

  emb_kernel<<<ROWS / 4, 256, 0, stream>>>(ids, tok, pos, xA);

  for (int l = 0; l < L_; l++) {
    gemm_mfma<128, 0><<<dim3(768 / 128, ROWS / 128), 512, 0, stream>>>(
        xA, Wqkv + (size_t)l * 768 * 256, bqkv + l * 768, big, ROWS, 768, 256);
    attn_mfma<<<B_ * H_, 512, 0, stream>>>(big, ob);
    gemm_mfma<64, 0><<<dim3(256 / 128, ROWS / 64), 512, 0, stream>>>(
        ob, Wo + (size_t)l * 256 * 256, bo + l * 256, pb, ROWS, 256, 256);
    add_ln<<<ROWS / 4, 256, 0, stream>>>(xA, pb, ln1g + l * 256, ln1b + l * 256, xB);
    gemm_mfma<128, 1><<<dim3(1024 / 128, ROWS / 128), 512, 0, stream>>>(
        xB, W1 + (size_t)l * 1024 * 256, b1 + l * 1024, big, ROWS, 1024, 256);
    gemm_mfma<64, 0><<<dim3(256 / 128, ROWS / 64), 512, 0, stream>>>(
        big, W2 + (size_t)l * 256 * 1024, b2 + l * 256, pb, ROWS, 256, 1024);
    add_ln<<<ROWS / 4, 256, 0, stream>>>(xB, pb, ln2g + l * 256, ln2b + l * 256, xA);
  }

  // gate MLP: t = relu(h @ Wg1^T + bg1)  -> mask
  gemm_mfma<64, 1><<<dim3(256 / 128, ROWS / 64), 512, 0, stream>>>(
      xA, Wg1, bg1, ob, ROWS, 256, 256);
  gate_mask<<<ROWS / 4, 256, 0, stream>>>(ob, Wg2, bg2, mask);
  scan_kernel<<<1, 256, 0, stream>>>(mask, slots, cnt);
  (void)hipMemsetAsync(mem, 0, (size_t)M_ * D_ * sizeof(float), stream);
  scatter_kernel<<<ROWS / 4, 256, 0, stream>>>(xA, slots, mem);

  qnorm_kernel<<<B_ / 4, 256, 0, stream>>>(xA, qden);
  sims_kernel<<<M_ / 4, 256, 0, stream>>>(xA, mem, qden, cnt, sims);
  topk_mix<<<B_, 256, 0, stream>>>(xA, mem, sims, cnt, Wc, bc, out);
}

// Round 8
// 471.852 us; speedup vs baseline: 1.0766x; 1.0766x over previous
//
#include <hip/hip_runtime.h>
#include <math.h>

#define D_   256
#define H_   8
#define L_   2
#define FF_  1024
#define S_   512
#define B_   32
#define M_   4096
#define NC_  10
#define ROWS (B_*S_)   // 16384

typedef __attribute__((ext_vector_type(8))) short bf16x8;
typedef __attribute__((ext_vector_type(4))) float f32x4;

__device__ __forceinline__ float wave_sum(float v) {
#pragma unroll
  for (int off = 1; off < 64; off <<= 1) v += __shfl_xor(v, off, 64);
  return v;
}

__device__ __forceinline__ unsigned short bf16_rne(float x) {
  unsigned int b = __float_as_uint(x);
  return (unsigned short)((b + 0x7FFFu + ((b >> 16) & 1u)) >> 16);
}
__device__ __forceinline__ float bf16_f(unsigned short h) {
  return __uint_as_float(((unsigned int)h) << 16);
}
__device__ __forceinline__ unsigned int cvt_pk_bf16(float a, float b) {
  unsigned int r;
  asm volatile("v_cvt_pk_bf16_f32 %0, %1, %2" : "=v"(r) : "v"(a), "v"(b));
  return r;
}

// convert float4 -> hi/lo bf16 quads, store 8B each (8B-aligned offsets)
__device__ __forceinline__ void cvt_store(unsigned short* Hq, unsigned short* Lq,
                                          int off, float4 v) {
  float f[4] = {v.x, v.y, v.z, v.w};
  unsigned short h[4], l[4];
#pragma unroll
  for (int i = 0; i < 4; i++) {
    h[i] = bf16_rne(f[i]);
    l[i] = bf16_rne(f[i] - bf16_f(h[i]));
  }
  uint2 hp, lp;
  hp.x = (unsigned int)h[0] | ((unsigned int)h[1] << 16);
  hp.y = (unsigned int)h[2] | ((unsigned int)h[3] << 16);
  lp.x = (unsigned int)l[0] | ((unsigned int)l[1] << 16);
  lp.y = (unsigned int)l[2] | ((unsigned int)l[3] << 16);
  *(uint2*)&Hq[off] = hp;
  *(uint2*)&Lq[off] = lp;
}

// conflict-free b64-pair fragment load (rows at 72B/1032B stride)
__device__ __forceinline__ bf16x8 ld_frag(const unsigned short* p, int off) {
  union { uint2 u[2]; bf16x8 v; } x;
  x.u[0] = *(const uint2*)(p + off);
  x.u[1] = *(const uint2*)(p + off + 4);
  return x.v;
}

// ---------------- embedding ----------------
__global__ __launch_bounds__(256) void emb_kernel(const int* __restrict__ ids,
                                                  const float* __restrict__ tok,
                                                  const float* __restrict__ pos,
                                                  float* __restrict__ x) {
  const int row  = blockIdx.x * 4 + (threadIdx.x >> 6);
  const int lane = threadIdx.x & 63;
  const int id = ids[row];
  const int s  = row & (S_ - 1);
  const float4 t = *(const float4*)(tok + (size_t)id * D_ + lane * 4);
  const float4 p = *(const float4*)(pos + (size_t)s  * D_ + lane * 4);
  float4 r; r.x = t.x + p.x; r.y = t.y + p.y; r.z = t.z + p.z; r.w = t.w + p.w;
  *(float4*)(x + (size_t)row * D_ + lane * 4) = r;
}

// ---- split-bf16 MFMA GEMM: C[M,N] = A[M,K]*W[N,K]^T + bias (+ReLU) --------
// pitch 36 u16 (72B): 18-bank row stride -> conflict-free b64 reads/writes.
// Register prefetch of next k-tile (T14 async-stage).
#define LP 36
template<int BM, int RELU>
__global__ __launch_bounds__(512, 4) void gemm_mfma(const float* __restrict__ A,
                                                    const float* __restrict__ Bm,
                                                    const float* __restrict__ bias,
                                                    float* __restrict__ C,
                                                    int M, int N, int K) {
  constexpr int WGM = BM / 64;
  constexpr int WGN = 8 / WGM;
  constexpr int WN  = 128 / WGN;
  constexpr int FN  = WN / 16;
  __shared__ __align__(16) unsigned short Ah[BM * LP];
  __shared__ __align__(16) unsigned short Al[BM * LP];
  __shared__ __align__(16) unsigned short Bh[128 * LP];
  __shared__ __align__(16) unsigned short Bl[128 * LP];

  const int tid  = threadIdx.x;
  const int lane = tid & 63;
  const int wid  = tid >> 6;
  const int wm = wid / WGN, wn = wid % WGN;
  const int m0 = blockIdx.y * BM, n0 = blockIdx.x * 128;
  const int lrow  = lane & 15;
  const int khalf = (lane >> 4) * 8;

  const int srow = tid >> 3;            // 0..63 staging row (+j*64)
  const int kq   = (tid & 7) << 2;      // 0,4,..28 k offset
  const float* Aptr = A + (size_t)(m0 + srow) * K + kq;
  const float* Bptr = Bm + (size_t)(n0 + srow) * K + kq;

  f32x4 acc[4][FN];
#pragma unroll
  for (int i = 0; i < 4; i++)
#pragma unroll
    for (int j = 0; j < FN; j++) acc[i][j] = (f32x4){0.f, 0.f, 0.f, 0.f};

  float4 pa[BM / 64], pb[2];
#pragma unroll
  for (int j = 0; j < BM / 64; j++) pa[j] = *(const float4*)(Aptr + (size_t)j * 64 * K);
#pragma unroll
  for (int j = 0; j < 2; j++) pb[j] = *(const float4*)(Bptr + (size_t)j * 64 * K);

  for (int k0 = 0; k0 < K; k0 += 32) {
    // prefetch next tile into regs (consumed next iteration)
    const int kn = (k0 + 32 < K) ? (k0 + 32) : k0;
    float4 na[BM / 64], nb[2];
#pragma unroll
    for (int j = 0; j < BM / 64; j++) na[j] = *(const float4*)(Aptr + (size_t)j * 64 * K + kn);
#pragma unroll
    for (int j = 0; j < 2; j++) nb[j] = *(const float4*)(Bptr + (size_t)j * 64 * K + kn);

    __syncthreads();
#pragma unroll
    for (int j = 0; j < BM / 64; j++)
      cvt_store(Ah, Al, (srow + j * 64) * LP + kq, pa[j]);
#pragma unroll
    for (int j = 0; j < 2; j++)
      cvt_store(Bh, Bl, (srow + j * 64) * LP + kq, pb[j]);
    __syncthreads();

    bf16x8 ah[4], al[4], bh[FN], bl[FN];
#pragma unroll
    for (int fm = 0; fm < 4; fm++) {
      const int r = (wm * 64 + fm * 16 + lrow) * LP + khalf;
      ah[fm] = ld_frag(Ah, r);
      al[fm] = ld_frag(Al, r);
    }
#pragma unroll
    for (int fn = 0; fn < FN; fn++) {
      const int r = (wn * WN + fn * 16 + lrow) * LP + khalf;
      bh[fn] = ld_frag(Bh, r);
      bl[fn] = ld_frag(Bl, r);
    }
#pragma unroll
    for (int fm = 0; fm < 4; fm++)
#pragma unroll
      for (int fn = 0; fn < FN; fn++) {
        acc[fm][fn] = __builtin_amdgcn_mfma_f32_16x16x32_bf16(ah[fm], bh[fn], acc[fm][fn], 0, 0, 0);
        acc[fm][fn] = __builtin_amdgcn_mfma_f32_16x16x32_bf16(ah[fm], bl[fn], acc[fm][fn], 0, 0, 0);
        acc[fm][fn] = __builtin_amdgcn_mfma_f32_16x16x32_bf16(al[fm], bh[fn], acc[fm][fn], 0, 0, 0);
      }
#pragma unroll
    for (int j = 0; j < BM / 64; j++) pa[j] = na[j];
#pragma unroll
    for (int j = 0; j < 2; j++) pb[j] = nb[j];
  }

#pragma unroll
  for (int fm = 0; fm < 4; fm++)
#pragma unroll
    for (int fn = 0; fn < FN; fn++) {
      const int mrow = m0 + wm * 64 + fm * 16 + (lane >> 4) * 4;
      const int ncol = n0 + wn * WN + fn * 16 + (lane & 15);
      const float bi = bias[ncol];
#pragma unroll
      for (int r = 0; r < 4; r++) {
        float v = acc[fm][fn][r] + bi;
        if (RELU) v = fmaxf(v, 0.f);
        C[(size_t)(mrow + r) * N + ncol] = v;
      }
    }
}

// ---------------- MFMA attention (zero-shuffle PV via K-row permutation) ----
// Block = (b,h), 1024 threads (16 waves x 32 q rows). K rows stored PERMUTED
// in LDS (slot s = 16u+4g+r holds orig k = 8g+4u+r within each 32-tile) so
// the S^T=mfma(K',Q) output registers are exactly the PV B-fragment. V^T
// stays in original k order; l-sum and PV are permutation-invariant.
#define KP 36    // u16/row: 72B stride, conflict-free b64
#define VP 516   // u16/row: 1032B stride, conflict-free b64
__global__ __launch_bounds__(1024, 4) void attn_mfma(const float* __restrict__ qkv,
                                                     float* __restrict__ o) {
  __shared__ __align__(16) unsigned short Kh[512 * KP];
  __shared__ __align__(16) unsigned short Kl[512 * KP];
  __shared__ __align__(16) unsigned short Vth[32 * VP];
  __shared__ __align__(16) unsigned short Vtl[32 * VP];

  const int bh = blockIdx.x;
  const int b = bh >> 3, h = bh & 7;
  const int tid = threadIdx.x;
  const int lane = tid & 63;
  const int wv = tid >> 6;
  const float* base = qkv + (size_t)b * (S_ * 768) + h * 32;

  // ---- stage: threads 0..511 -> K (one slot-row each, permuted);
  //             threads 512..1023 -> V^T (16 d x one k-pair each) ----------
  if (tid < 512) {
    const int slot = tid;
    const int s5 = slot & 31;
    const int orig = (slot & ~31) + 8 * ((s5 >> 2) & 3) + ((s5 >> 4) << 2) + (s5 & 3);
    const float* p = base + (size_t)orig * 768 + 256;
#pragma unroll
    for (int j = 0; j < 8; j++) {
      const float4 v = *(const float4*)(p + j * 4);
      cvt_store(Kh, Kl, slot * KP + j * 4, v);
    }
  } else {
    const int u  = tid - 512;
    const int kp = u & 255;            // k rows 2kp, 2kp+1
    const int dg = (u >> 8) * 16;      // d block 0 or 16
    const float* p0 = base + (size_t)(2 * kp) * 768 + 512 + dg;
    const float* p1 = p0 + 768;
    float v0[16], v1[16];
#pragma unroll
    for (int i = 0; i < 4; i++) {
      *(float4*)&v0[i * 4] = *(const float4*)(p0 + i * 4);
      *(float4*)&v1[i * 4] = *(const float4*)(p1 + i * 4);
    }
#pragma unroll
    for (int d = 0; d < 16; d++) {
      const unsigned short h0 = bf16_rne(v0[d]), h1 = bf16_rne(v1[d]);
      const unsigned short l0 = bf16_rne(v0[d] - bf16_f(h0));
      const unsigned short l1 = bf16_rne(v1[d] - bf16_f(h1));
      *(unsigned int*)&Vth[(dg + d) * VP + 2 * kp] = (unsigned int)h0 | ((unsigned int)h1 << 16);
      *(unsigned int*)&Vtl[(dg + d) * VP + 2 * kp] = (unsigned int)l0 | ((unsigned int)l1 << 16);
    }
  }

  // ---- per-wave Q B-fragments (scale folded in) ----------------------------
  const int q0 = wv * 32;
  bf16x8 qh[2], ql[2];
#pragma unroll
  for (int f = 0; f < 2; f++) {
    const float* qp = base + (size_t)(q0 + f * 16 + (lane & 15)) * 768 + ((lane >> 4) * 8);
    float qq[8];
    *(float4*)&qq[0] = *(const float4*)qp;
    *(float4*)&qq[4] = *(const float4*)(qp + 4);
    bf16x8 vh, vl;
#pragma unroll
    for (int j = 0; j < 8; j++) {
      const float sv = qq[j] * 0.17677669529663687f;
      const unsigned short hh = bf16_rne(sv);
      vh[j] = (short)hh;
      vl[j] = (short)bf16_rne(sv - bf16_f(hh));
    }
    qh[f] = vh; ql[f] = vl;
  }

  __syncthreads();

  f32x4 oacc[2][2];   // [d-frag][q-frag], O^T: row=d, col=q
#pragma unroll
  for (int i = 0; i < 2; i++)
#pragma unroll
    for (int j = 0; j < 2; j++) oacc[i][j] = (f32x4){0.f, 0.f, 0.f, 0.f};
  float lacc[2] = {0.f, 0.f};

  for (int kt = 0; kt < S_; kt += 32) {
    bf16x8 kah[2], kal[2];
#pragma unroll
    for (int u = 0; u < 2; u++) {
      const int off = (kt + u * 16 + (lane & 15)) * KP + ((lane >> 4) * 8);
      kah[u] = ld_frag(Kh, off);
      kal[u] = ld_frag(Kl, off);
    }
    bf16x8 vah[2], val[2];
#pragma unroll
    for (int df = 0; df < 2; df++) {
      const int off = (df * 16 + (lane & 15)) * VP + kt + ((lane >> 4) * 8);
      vah[df] = ld_frag(Vth, off);
      val[df] = ld_frag(Vtl, off);
    }
    // S^T = K' . Q^T (3-term split); output slot rows are the permuted k's
    f32x4 s[2][2];
#pragma unroll
    for (int u = 0; u < 2; u++)
#pragma unroll
      for (int f = 0; f < 2; f++) {
        f32x4 a = (f32x4){0.f, 0.f, 0.f, 0.f};
        a = __builtin_amdgcn_mfma_f32_16x16x32_bf16(kal[u], qh[f], a, 0, 0, 0);
        a = __builtin_amdgcn_mfma_f32_16x16x32_bf16(kah[u], ql[f], a, 0, 0, 0);
        a = __builtin_amdgcn_mfma_f32_16x16x32_bf16(kah[u], qh[f], a, 0, 0, 0);
        s[u][f] = a;
      }
    // exp + pack: registers already ARE the PV B-fragment (no shuffles)
#pragma unroll
    for (int f = 0; f < 2; f++) {
      union { unsigned int w[4]; bf16x8 v; } ph, pl;
#pragma unroll
      for (int u = 0; u < 2; u++) {
        const float p0 = __expf(s[u][f][0]);
        const float p1 = __expf(s[u][f][1]);
        const float p2 = __expf(s[u][f][2]);
        const float p3 = __expf(s[u][f][3]);
        lacc[f] += (p0 + p1) + (p2 + p3);
        const unsigned int h01 = cvt_pk_bf16(p0, p1);
        const unsigned int h23 = cvt_pk_bf16(p2, p3);
        const float r0 = p0 - __uint_as_float(h01 << 16);
        const float r1 = p1 - __uint_as_float(h01 & 0xffff0000u);
        const float r2 = p2 - __uint_as_float(h23 << 16);
        const float r3 = p3 - __uint_as_float(h23 & 0xffff0000u);
        ph.w[u * 2 + 0] = h01;
        ph.w[u * 2 + 1] = h23;
        pl.w[u * 2 + 0] = cvt_pk_bf16(r0, r1);
        pl.w[u * 2 + 1] = cvt_pk_bf16(r2, r3);
      }
#pragma unroll
      for (int df = 0; df < 2; df++) {
        oacc[df][f] = __builtin_amdgcn_mfma_f32_16x16x32_bf16(val[df], ph.v, oacc[df][f], 0, 0, 0);
        oacc[df][f] = __builtin_amdgcn_mfma_f32_16x16x32_bf16(vah[df], pl.v, oacc[df][f], 0, 0, 0);
        oacc[df][f] = __builtin_amdgcn_mfma_f32_16x16x32_bf16(vah[df], ph.v, oacc[df][f], 0, 0, 0);
      }
    }
  }

#pragma unroll
  for (int f = 0; f < 2; f++) {
    lacc[f] += __shfl_xor(lacc[f], 16, 64);
    lacc[f] += __shfl_xor(lacc[f], 32, 64);
  }
#pragma unroll
  for (int f = 0; f < 2; f++) {
    const float inv = 1.f / lacc[f];
    const int q = q0 + f * 16 + (lane & 15);
    float* op = o + (size_t)(b * S_ + q) * D_ + h * 32;
#pragma unroll
    for (int df = 0; df < 2; df++) {
      const int dbase = df * 16 + (lane >> 4) * 4;
#pragma unroll
      for (int r = 0; r < 4; r++)
        op[dbase + r] = oacc[df][f][r] * inv;
    }
  }
}

// ---------------- fused residual + layernorm (one wave per row) -------------
__global__ __launch_bounds__(256) void add_ln(const float* __restrict__ x,
                                              const float* __restrict__ y,
                                              const float* __restrict__ g,
                                              const float* __restrict__ bta,
                                              float* __restrict__ out) {
  const int row  = blockIdx.x * 4 + (threadIdx.x >> 6);
  const int lane = threadIdx.x & 63;
  const size_t base = (size_t)row * D_ + lane * 4;
  const float4 xv = *(const float4*)(x + base);
  const float4 yv = *(const float4*)(y + base);
  float v[4] = {xv.x + yv.x, xv.y + yv.y, xv.z + yv.z, xv.w + yv.w};
  float s = v[0] + v[1] + v[2] + v[3];
  s = wave_sum(s);
  const float mean = s * (1.f / 256.f);
  float d[4] = {v[0] - mean, v[1] - mean, v[2] - mean, v[3] - mean};
  float sq = d[0] * d[0] + d[1] * d[1] + d[2] * d[2] + d[3] * d[3];
  sq = wave_sum(sq);
  const float inv = 1.f / sqrtf(sq * (1.f / 256.f) + 1e-5f);
  const float4 gv = *(const float4*)(g + lane * 4);
  const float4 bv = *(const float4*)(bta + lane * 4);
  float4 r;
  r.x = d[0] * inv * gv.x + bv.x; r.y = d[1] * inv * gv.y + bv.y;
  r.z = d[2] * inv * gv.z + bv.z; r.w = d[3] * inv * gv.w + bv.w;
  *(float4*)(out + base) = r;
}

// ---------------- gate logit -> mask ----------------------------------------
__global__ __launch_bounds__(256) void gate_mask(const float* __restrict__ t,
                                                 const float* __restrict__ Wg2,
                                                 const float* __restrict__ bg2,
                                                 int* __restrict__ mask) {
  const int row  = blockIdx.x * 4 + (threadIdx.x >> 6);
  const int lane = threadIdx.x & 63;
  const float4 tv = *(const float4*)(t + (size_t)row * D_ + lane * 4);
  const float4 wv = *(const float4*)(Wg2 + lane * 4);
  float s = tv.x * wv.x + tv.y * wv.y + tv.z * wv.z + tv.w * wv.w;
  s = wave_sum(s);
  if (lane == 0) mask[row] = (s + bg2[0]) > 0.f ? 1 : 0;
}

// -------- parallel prefix-scan over 16384 masks (sequential semantics) ------
__global__ __launch_bounds__(256) void scan_kernel(const int* __restrict__ mask,
                                                   int* __restrict__ slots,
                                                   int* __restrict__ countp) {
  __shared__ int wtot[4];
  const int tid = threadIdx.x;
  const int lane = tid & 63, wid = tid >> 6;
  const int base = tid * 64;
  int s = 0;
#pragma unroll 8
  for (int i = 0; i < 64; i++) s += mask[base + i];
  int inc = s;
#pragma unroll
  for (int off = 1; off < 64; off <<= 1) {
    const int t = __shfl_up(inc, off, 64);
    if (lane >= off) inc += t;
  }
  if (lane == 63) wtot[wid] = inc;
  __syncthreads();
  int woff = 0;
#pragma unroll
  for (int w = 0; w < 4; w++) woff += (w < wid) ? wtot[w] : 0;
  const int total = wtot[0] + wtot[1] + wtot[2] + wtot[3];
  if (tid == 0) countp[0] = total < M_ ? total : M_;
  int run = woff + inc - s;
  for (int i = 0; i < 64; i++) {
    const int r = base + i;
    const int mk = mask[r];
    slots[r] = (mk && run < M_) ? run : -1;
    run += mk;
  }
}

// ---------------- scatter selected rows into memory -------------------------
__global__ __launch_bounds__(256) void scatter_kernel(const float* __restrict__ h,
                                                      const int* __restrict__ slots,
                                                      float* __restrict__ mem) {
  const int row  = blockIdx.x * 4 + (threadIdx.x >> 6);
  const int lane = threadIdx.x & 63;
  const int sl = slots[row];
  if (sl >= 0)
    *(float4*)(mem + (size_t)sl * D_ + lane * 4) =
        *(const float4*)(h + (size_t)row * D_ + lane * 4);
}

// ---------------- query norms (one wave per batch row) ----------------------
__global__ __launch_bounds__(256) void qnorm_kernel(const float* __restrict__ h,
                                                    float* __restrict__ qden) {
  const int b    = blockIdx.x * 4 + (threadIdx.x >> 6);
  const int lane = threadIdx.x & 63;
  const float4 c = *(const float4*)(h + (size_t)b * S_ * D_ + lane * 4);
  float sq = c.x * c.x + c.y * c.y + c.z * c.z + c.w * c.w;
  sq = wave_sum(sq);
  if (lane == 0) qden[b] = sqrtf(sq) + 1e-8f;
}

// ------- sims[b][r] for all 32 b: one wave per memory row r -----------------
__global__ __launch_bounds__(256) void sims_kernel(const float* __restrict__ h,
                                                   const float* __restrict__ mem,
                                                   const float* __restrict__ qden,
                                                   const int* __restrict__ countp,
                                                   float* __restrict__ sims) {
  __shared__ float cls[B_ * D_];
  __shared__ float qd[B_];
  const int tid = threadIdx.x;
  const int lane = tid & 63, wid = tid >> 6;
  for (int i = tid; i < B_ * D_ / 4; i += 256) {
    const int flat = i * 4;
    const int b = flat >> 8, d = flat & 255;
    *(float4*)&cls[flat] = *(const float4*)(h + (size_t)b * S_ * D_ + d);
  }
  if (tid < B_) qd[tid] = qden[tid];
  __syncthreads();
  const int count = countp[0];
  const int r = blockIdx.x * 4 + wid;
  const float4 m4 = *(const float4*)(mem + (size_t)r * D_ + lane * 4);
  float sq = m4.x * m4.x + m4.y * m4.y + m4.z * m4.z + m4.w * m4.w;
  sq = wave_sum(sq);
  const float rn = sqrtf(sq) + 1e-8f;
  if (r < count) {
    for (int b = 0; b < B_; b++) {
      const float4 c4 = *(const float4*)&cls[b * D_ + lane * 4];
      float dt = m4.x * c4.x + m4.y * c4.y + m4.z * c4.z + m4.w * c4.w;
      dt = wave_sum(dt);
      if (lane == 0) sims[b * M_ + r] = dt / (qd[b] * rn);
    }
  } else if (lane == 0) {
    for (int b = 0; b < B_; b++) sims[b * M_ + r] = -1e9f;
  }
}

// ---------------- per-batch: top-4 (wave-parallel argmax), mix, classifier --
__global__ __launch_bounds__(256) void topk_mix(const float* __restrict__ h,
                                                const float* __restrict__ mem,
                                                const float* __restrict__ simsg,
                                                const int* __restrict__ countp,
                                                const float* __restrict__ Wc,
                                                const float* __restrict__ bc,
                                                float* __restrict__ out) {
  __shared__ float sims[M_];
  __shared__ float cls[D_];
  __shared__ float wv4[4];
  __shared__ int   wi4[4];
  __shared__ float aug[D_];
  __shared__ float tv[4];
  __shared__ int   tix[4];

  const int b = blockIdx.x, tid = threadIdx.x;
  const int lane = tid & 63, wid = tid >> 6;
  const int count = countp[0];

  for (int i = tid; i < M_; i += 256) sims[i] = simsg[b * M_ + i];
  cls[tid] = h[(size_t)b * S_ * D_ + tid];
  __syncthreads();

  for (int k = 0; k < 4; k++) {
    float bv = -INFINITY; int bi = 1 << 30;
#pragma unroll
    for (int rr = 0; rr < M_ / 256; rr++) {
      const int r = tid + rr * 256;
      const float v = sims[r];
      if (v > bv || (v == bv && r < bi)) { bv = v; bi = r; }
    }
#pragma unroll
    for (int off = 1; off < 64; off <<= 1) {
      const float ov = __shfl_xor(bv, off, 64);
      const int   oi = __shfl_xor(bi, off, 64);
      if (ov > bv || (ov == bv && oi < bi)) { bv = ov; bi = oi; }
    }
    if (lane == 0) { wv4[wid] = bv; wi4[wid] = bi; }
    __syncthreads();
    if (tid == 0) {
      float bb = wv4[0]; int bbi = wi4[0];
#pragma unroll
      for (int i = 1; i < 4; i++)
        if (wv4[i] > bb || (wv4[i] == bb && wi4[i] < bbi)) { bb = wv4[i]; bbi = wi4[i]; }
      tv[k] = bb; tix[k] = bbi; sims[bbi] = -INFINITY;
    }
    __syncthreads();
  }

  float w[4];
  {
    const float mx = tv[0];
    float ws = 0.f;
#pragma unroll
    for (int k = 0; k < 4; k++) { w[k] = expf(tv[k] - mx); ws += w[k]; }
    const float inv = 1.f / ws;
#pragma unroll
    for (int k = 0; k < 4; k++) w[k] *= inv;
  }

  {
    float mv = 0.f;
    if (count > 0) {
#pragma unroll
      for (int k = 0; k < 4; k++) mv = fmaf(w[k], mem[(size_t)tix[k] * D_ + tid], mv);
    }
    aug[tid] = cls[tid] + mv;
  }
  __syncthreads();

  const float4 a4 = *(const float4*)&aug[lane * 4];
  for (int c = wid; c < NC_; c += 4) {
    const float4 wc = *(const float4*)(Wc + (size_t)c * D_ + lane * 4);
    float dt = a4.x * wc.x + a4.y * wc.y + a4.z * wc.z + a4.w * wc.w;
    dt = wave_sum(dt);
    if (lane == 0) out[b * NC_ + c] = dt + bc[c];
  }
}

// ---------------- launcher ---------------------------------------------------
extern "C" void kernel_launch(void* const* d_in, const int* in_sizes, int n_in,
                              void* d_out, int out_size, void* d_ws, size_t ws_size,
                              hipStream_t stream) {
  const int*   ids  = (const int*)d_in[0];
  const float* tok  = (const float*)d_in[1];
  const float* pos  = (const float*)d_in[2];
  const float* Wqkv = (const float*)d_in[3];
  const float* bqkv = (const float*)d_in[4];
  const float* Wo   = (const float*)d_in[5];
  const float* bo   = (const float*)d_in[6];
  const float* ln1g = (const float*)d_in[7];
  const float* ln1b = (const float*)d_in[8];
  const float* W1   = (const float*)d_in[9];
  const float* b1   = (const float*)d_in[10];
  const float* W2   = (const float*)d_in[11];
  const float* b2   = (const float*)d_in[12];
  const float* ln2g = (const float*)d_in[13];
  const float* ln2b = (const float*)d_in[14];
  const float* Wg1  = (const float*)d_in[15];
  const float* bg1  = (const float*)d_in[16];
  const float* Wg2  = (const float*)d_in[17];
  const float* bg2  = (const float*)d_in[18];
  const float* Wc   = (const float*)d_in[19];
  const float* bc   = (const float*)d_in[20];
  float* out = (float*)d_out;

  float* xA   = (float*)d_ws;
  float* xB   = xA  + (size_t)ROWS * D_;
  float* ob   = xB  + (size_t)ROWS * D_;
  float* pb   = ob  + (size_t)ROWS * D_;
  float* big  = pb  + (size_t)ROWS * D_;
  float* mem  = big + (size_t)ROWS * FF_;
  float* qden = mem + (size_t)M_ * D_;
  float* sims = qden + 64;
  int*   mask = (int*)(sims + (size_t)B_ * M_);
  int*   slots = mask + ROWS;
  int*   cnt   = slots + ROWS;

  emb_kernel<<<ROWS / 4, 256, 0, stream>>>(ids, tok, pos, xA);

  for (int l = 0; l < L_; l++) {
    gemm_mfma<128, 0><<<dim3(768 / 128, ROWS / 128), 512, 0, stream>>>(
        xA, Wqkv + (size_t)l * 768 * 256, bqkv + l * 768, big, ROWS, 768, 256);
    attn_mfma<<<B_ * H_, 1024, 0, stream>>>(big, ob);
    gemm_mfma<64, 0><<<dim3(256 / 128, ROWS / 64), 512, 0, stream>>>(
        ob, Wo + (size_t)l * 256 * 256, bo + l * 256, pb, ROWS, 256, 256);
    add_ln<<<ROWS / 4, 256, 0, stream>>>(xA, pb, ln1g + l * 256, ln1b + l * 256, xB);
    gemm_mfma<128, 1><<<dim3(1024 / 128, ROWS / 128), 512, 0, stream>>>(
        xB, W1 + (size_t)l * 1024 * 256, b1 + l * 1024, big, ROWS, 1024, 256);
    gemm_mfma<64, 0><<<dim3(256 / 128, ROWS / 64), 512, 0, stream>>>(
        big, W2 + (size_t)l * 256 * 1024, b2 + l * 256, pb, ROWS, 256, 1024);
    add_ln<<<ROWS / 4, 256, 0, stream>>>(xB, pb, ln2g + l * 256, ln2b + l * 256, xA);
  }

  // gate MLP: t = relu(h @ Wg1^T + bg1)  -> mask
  gemm_mfma<64, 1><<<dim3(256 / 128, ROWS / 64), 512, 0, stream>>>(
      xA, Wg1, bg1, ob, ROWS, 256, 256);
  gate_mask<<<ROWS / 4, 256, 0, stream>>>(ob, Wg2, bg2, mask);
  scan_kernel<<<1, 256, 0, stream>>>(mask, slots, cnt);
  (void)hipMemsetAsync(mem, 0, (size_t)M_ * D_ * sizeof(float), stream);
  scatter_kernel<<<ROWS / 4, 256, 0, stream>>>(xA, slots, mem);

  qnorm_kernel<<<B_ / 4, 256, 0, stream>>>(xA, qden);
  sims_kernel<<<M_ / 4, 256, 0, stream>>>(xA, mem, qden, cnt, sims);
  topk_mix<<<B_, 256, 0, stream>>>(xA, mem, sims, cnt, Wc, bc, out);
}

// Round 9
// 455.386 us; speedup vs baseline: 1.1156x; 1.0362x over previous
//
#include <hip/hip_runtime.h>
#include <math.h>

#define D_   256
#define H_   8
#define L_   2
#define FF_  1024
#define S_   512
#define B_   32
#define M_   4096
#define NC_  10
#define ROWS (B_*S_)   // 16384

typedef __attribute__((ext_vector_type(8))) short bf16x8;
typedef __attribute__((ext_vector_type(4))) float f32x4;
typedef unsigned int uint32;
typedef unsigned short ushort16;

__device__ __forceinline__ float wave_sum(float v) {
#pragma unroll
  for (int off = 1; off < 64; off <<= 1) v += __shfl_xor(v, off, 64);
  return v;
}

__device__ __forceinline__ unsigned short bf16_rne(float x) {
  unsigned int b = __float_as_uint(x);
  return (unsigned short)((b + 0x7FFFu + ((b >> 16) & 1u)) >> 16);
}
__device__ __forceinline__ float bf16_f(unsigned short h) {
  return __uint_as_float(((unsigned int)h) << 16);
}
// split x into hi/lo bf16, packed as hi | (lo<<16)
__device__ __forceinline__ uint32 pack_split(float x) {
  const unsigned short h = bf16_rne(x);
  const unsigned short l = bf16_rne(x - bf16_f(h));
  return (uint32)h | ((uint32)l << 16);
}
// 4 packed elems -> 8B hi-quad + 8B lo-quad into LDS planes
__device__ __forceinline__ void unpack_store(unsigned short* Hq, unsigned short* Lq,
                                             int off, uint4 v) {
  uint2 hp, lp;
  hp.x = (v.x & 0xffffu) | (v.y << 16);
  hp.y = (v.z & 0xffffu) | (v.w << 16);
  lp.x = (v.x >> 16) | (v.y & 0xffff0000u);
  lp.y = (v.z >> 16) | (v.w & 0xffff0000u);
  *(uint2*)&Hq[off] = hp;
  *(uint2*)&Lq[off] = lp;
}
// conflict-free b64-pair fragment load (rows at 72B/1032B stride)
__device__ __forceinline__ bf16x8 ld_frag(const unsigned short* p, int off) {
  union { uint2 u[2]; bf16x8 v; } x;
  x.u[0] = *(const uint2*)(p + off);
  x.u[1] = *(const uint2*)(p + off + 4);
  return x.v;
}

// ---------------- weight packing: fp32 -> packed split (vec4) ---------------
__global__ __launch_bounds__(256) void pack_f32(const float* __restrict__ src,
                                                uint32* __restrict__ dst, int n4) {
  const int i = blockIdx.x * 256 + threadIdx.x;
  if (i < n4) {
    const float4 v = ((const float4*)src)[i];
    uint4 o;
    o.x = pack_split(v.x); o.y = pack_split(v.y);
    o.z = pack_split(v.z); o.w = pack_split(v.w);
    ((uint4*)dst)[i] = o;
  }
}

// ---------------- embedding (fp32 + packed) ---------------------------------
__global__ __launch_bounds__(256) void emb_kernel(const int* __restrict__ ids,
                                                  const float* __restrict__ tok,
                                                  const float* __restrict__ pos,
                                                  float* __restrict__ x,
                                                  uint32* __restrict__ xp) {
  const int row  = blockIdx.x * 4 + (threadIdx.x >> 6);
  const int lane = threadIdx.x & 63;
  const int id = ids[row];
  const int s  = row & (S_ - 1);
  const float4 t = *(const float4*)(tok + (size_t)id * D_ + lane * 4);
  const float4 p = *(const float4*)(pos + (size_t)s  * D_ + lane * 4);
  float4 r; r.x = t.x + p.x; r.y = t.y + p.y; r.z = t.z + p.z; r.w = t.w + p.w;
  *(float4*)(x + (size_t)row * D_ + lane * 4) = r;
  uint4 o;
  o.x = pack_split(r.x); o.y = pack_split(r.y);
  o.z = pack_split(r.z); o.w = pack_split(r.w);
  *(uint4*)(xp + (size_t)row * D_ + lane * 4) = o;
}

// ---- split-bf16 MFMA GEMM, packed operands: C = A*W^T + bias (+ReLU) ------
// A,W pre-split (hi|lo<<16). pitch 36 u16 (72B): conflict-free-ish b64.
// XCD-bijective swizzle: orig = (bid&7)*(nwg/8) + (bid>>3).
#define LP 36
template<int BM, int RELU, int PACKOUT>
__global__ __launch_bounds__(512, 4) void gemm_mfma(const uint32* __restrict__ Ap,
                                                    const uint32* __restrict__ Bp,
                                                    const float* __restrict__ bias,
                                                    float* __restrict__ C,
                                                    uint32* __restrict__ Cp,
                                                    int M, int N, int K, int NX) {
  constexpr int WGM = BM / 64;
  constexpr int WGN = 8 / WGM;
  constexpr int WN  = 128 / WGN;
  constexpr int FN  = WN / 16;
  __shared__ __align__(16) unsigned short Ah[BM * LP];
  __shared__ __align__(16) unsigned short Al[BM * LP];
  __shared__ __align__(16) unsigned short Bh[128 * LP];
  __shared__ __align__(16) unsigned short Bl[128 * LP];

  const int q8 = gridDim.x >> 3;
  const int orig = (blockIdx.x & 7) * q8 + (blockIdx.x >> 3);
  const int by = orig / NX, bx = orig % NX;

  const int tid  = threadIdx.x;
  const int lane = tid & 63;
  const int wid  = tid >> 6;
  const int wm = wid / WGN, wn = wid % WGN;
  const int m0 = by * BM, n0 = bx * 128;
  const int lrow  = lane & 15;
  const int khalf = (lane >> 4) * 8;

  const int srow = tid >> 3;            // 0..63 staging row (+j*64)
  const int kq   = (tid & 7) << 2;      // 0,4,..28 k offset
  const uint32* Aptr = Ap + (size_t)(m0 + srow) * K + kq;
  const uint32* Bptr = Bp + (size_t)(n0 + srow) * K + kq;

  f32x4 acc[4][FN];
#pragma unroll
  for (int i = 0; i < 4; i++)
#pragma unroll
    for (int j = 0; j < FN; j++) acc[i][j] = (f32x4){0.f, 0.f, 0.f, 0.f};

  uint4 pa[BM / 64], pb[2];
#pragma unroll
  for (int j = 0; j < BM / 64; j++) pa[j] = *(const uint4*)(Aptr + (size_t)j * 64 * K);
#pragma unroll
  for (int j = 0; j < 2; j++) pb[j] = *(const uint4*)(Bptr + (size_t)j * 64 * K);

  for (int k0 = 0; k0 < K; k0 += 32) {
    const int kn = (k0 + 32 < K) ? (k0 + 32) : k0;
    uint4 na[BM / 64], nb[2];
#pragma unroll
    for (int j = 0; j < BM / 64; j++) na[j] = *(const uint4*)(Aptr + (size_t)j * 64 * K + kn);
#pragma unroll
    for (int j = 0; j < 2; j++) nb[j] = *(const uint4*)(Bptr + (size_t)j * 64 * K + kn);

    __syncthreads();
#pragma unroll
    for (int j = 0; j < BM / 64; j++)
      unpack_store(Ah, Al, (srow + j * 64) * LP + kq, pa[j]);
#pragma unroll
    for (int j = 0; j < 2; j++)
      unpack_store(Bh, Bl, (srow + j * 64) * LP + kq, pb[j]);
    __syncthreads();

    bf16x8 ah[4], al[4], bh[FN], bl[FN];
#pragma unroll
    for (int fm = 0; fm < 4; fm++) {
      const int r = (wm * 64 + fm * 16 + lrow) * LP + khalf;
      ah[fm] = ld_frag(Ah, r);
      al[fm] = ld_frag(Al, r);
    }
#pragma unroll
    for (int fn = 0; fn < FN; fn++) {
      const int r = (wn * WN + fn * 16 + lrow) * LP + khalf;
      bh[fn] = ld_frag(Bh, r);
      bl[fn] = ld_frag(Bl, r);
    }
#pragma unroll
    for (int fm = 0; fm < 4; fm++)
#pragma unroll
      for (int fn = 0; fn < FN; fn++) {
        acc[fm][fn] = __builtin_amdgcn_mfma_f32_16x16x32_bf16(ah[fm], bh[fn], acc[fm][fn], 0, 0, 0);
        acc[fm][fn] = __builtin_amdgcn_mfma_f32_16x16x32_bf16(ah[fm], bl[fn], acc[fm][fn], 0, 0, 0);
        acc[fm][fn] = __builtin_amdgcn_mfma_f32_16x16x32_bf16(al[fm], bh[fn], acc[fm][fn], 0, 0, 0);
      }
#pragma unroll
    for (int j = 0; j < BM / 64; j++) pa[j] = na[j];
#pragma unroll
    for (int j = 0; j < 2; j++) pb[j] = nb[j];
  }

#pragma unroll
  for (int fm = 0; fm < 4; fm++)
#pragma unroll
    for (int fn = 0; fn < FN; fn++) {
      const int mrow = m0 + wm * 64 + fm * 16 + (lane >> 4) * 4;
      const int ncol = n0 + wn * WN + fn * 16 + (lane & 15);
      const float bi = bias[ncol];
#pragma unroll
      for (int r = 0; r < 4; r++) {
        float v = acc[fm][fn][r] + bi;
        if (RELU) v = fmaxf(v, 0.f);
        if (PACKOUT) Cp[(size_t)(mrow + r) * N + ncol] = pack_split(v);
        else         C[(size_t)(mrow + r) * N + ncol] = v;
      }
    }
}

// ---------------- MFMA attention (packed in, packed out) --------------------
// Block = (b,h), 1024 threads (16 waves x 32 q rows). K permuted in LDS so
// S^T registers are the PV B-fragment (zero shuffles). No-max softmax.
#define KP 36    // u16/row: 72B stride
#define VP 516   // u16/row: 1032B stride
__global__ __launch_bounds__(1024, 4) void attn_mfma(const uint32* __restrict__ qkv,
                                                     uint32* __restrict__ o) {
  __shared__ __align__(16) unsigned short Kh[512 * KP];
  __shared__ __align__(16) unsigned short Kl[512 * KP];
  __shared__ __align__(16) unsigned short Vth[32 * VP];
  __shared__ __align__(16) unsigned short Vtl[32 * VP];

  const int q8g = gridDim.x >> 3;                 // 32
  const int obh = (blockIdx.x & 7) * q8g + (blockIdx.x >> 3);
  const int b = obh >> 3, h = obh & 7;
  const int tid = threadIdx.x;
  const int lane = tid & 63;
  const int wv = tid >> 6;
  const uint32* base = qkv + (size_t)b * (S_ * 768) + h * 32;

  // ---- stage: threads 0..511 -> K (one permuted slot-row each);
  //             threads 512..1023 -> V^T (16 d x one k-pair each) ----------
  if (tid < 512) {
    const int slot = tid;
    const int s5 = slot & 31;
    const int orig = (slot & ~31) + 8 * ((s5 >> 2) & 3) + ((s5 >> 4) << 2) + (s5 & 3);
    const uint32* p = base + (size_t)orig * 768 + 256;
#pragma unroll
    for (int j = 0; j < 8; j++)
      unpack_store(Kh, Kl, slot * KP + j * 4, *(const uint4*)(p + j * 4));
  } else {
    const int u  = tid - 512;
    const int kp = u & 255;            // k rows 2kp, 2kp+1
    const int dg = (u >> 8) * 16;      // d block 0 or 16
    const uint32* p0 = base + (size_t)(2 * kp) * 768 + 512 + dg;
    const uint32* p1 = p0 + 768;
    union { uint4 u4[4]; uint32 w[16]; } a0, a1;
#pragma unroll
    for (int i = 0; i < 4; i++) {
      a0.u4[i] = *(const uint4*)(p0 + i * 4);
      a1.u4[i] = *(const uint4*)(p1 + i * 4);
    }
#pragma unroll
    for (int d = 0; d < 16; d++) {
      const uint32 w0 = a0.w[d], w1 = a1.w[d];
      *(uint32*)&Vth[(dg + d) * VP + 2 * kp] = (w0 & 0xffffu) | (w1 << 16);
      *(uint32*)&Vtl[(dg + d) * VP + 2 * kp] = (w0 >> 16) | (w1 & 0xffff0000u);
    }
  }

  // ---- per-wave Q B-fragments (reconstruct, scale, re-split) --------------
  const int q0 = wv * 32;
  bf16x8 qh[2], ql[2];
#pragma unroll
  for (int f = 0; f < 2; f++) {
    const uint32* qp = base + (size_t)(q0 + f * 16 + (lane & 15)) * 768 + ((lane >> 4) * 8);
    union { uint4 u4[2]; uint32 w[8]; } qu;
    qu.u4[0] = *(const uint4*)qp;
    qu.u4[1] = *(const uint4*)(qp + 4);
    bf16x8 vh, vl;
#pragma unroll
    for (int j = 0; j < 8; j++) {
      const uint32 p = qu.w[j];
      const float qf = __uint_as_float(p << 16) + __uint_as_float(p & 0xffff0000u);
      const float sv = qf * 0.17677669529663687f;
      const unsigned short hh = bf16_rne(sv);
      vh[j] = (short)hh;
      vl[j] = (short)bf16_rne(sv - bf16_f(hh));
    }
    qh[f] = vh; ql[f] = vl;
  }

  __syncthreads();

  f32x4 oacc[2][2];   // [d-frag][q-frag], O^T: row=d, col=q
#pragma unroll
  for (int i = 0; i < 2; i++)
#pragma unroll
    for (int j = 0; j < 2; j++) oacc[i][j] = (f32x4){0.f, 0.f, 0.f, 0.f};
  float lacc[2] = {0.f, 0.f};

  for (int kt = 0; kt < S_; kt += 32) {
    bf16x8 kah[2], kal[2];
#pragma unroll
    for (int u = 0; u < 2; u++) {
      const int off = (kt + u * 16 + (lane & 15)) * KP + ((lane >> 4) * 8);
      kah[u] = ld_frag(Kh, off);
      kal[u] = ld_frag(Kl, off);
    }
    bf16x8 vah[2], val[2];
#pragma unroll
    for (int df = 0; df < 2; df++) {
      const int off = (df * 16 + (lane & 15)) * VP + kt + ((lane >> 4) * 8);
      vah[df] = ld_frag(Vth, off);
      val[df] = ld_frag(Vtl, off);
    }
    f32x4 s[2][2];
#pragma unroll
    for (int u = 0; u < 2; u++)
#pragma unroll
      for (int f = 0; f < 2; f++) {
        f32x4 a = (f32x4){0.f, 0.f, 0.f, 0.f};
        a = __builtin_amdgcn_mfma_f32_16x16x32_bf16(kal[u], qh[f], a, 0, 0, 0);
        a = __builtin_amdgcn_mfma_f32_16x16x32_bf16(kah[u], ql[f], a, 0, 0, 0);
        a = __builtin_amdgcn_mfma_f32_16x16x32_bf16(kah[u], qh[f], a, 0, 0, 0);
        s[u][f] = a;
      }
#pragma unroll
    for (int f = 0; f < 2; f++) {
      union { uint32 w[4]; bf16x8 v; } ph, pl;
#pragma unroll
      for (int u = 0; u < 2; u++) {
        const float p0 = __expf(s[u][f][0]);
        const float p1 = __expf(s[u][f][1]);
        const float p2 = __expf(s[u][f][2]);
        const float p3 = __expf(s[u][f][3]);
        lacc[f] += (p0 + p1) + (p2 + p3);
        unsigned int h01, h23;
        asm volatile("v_cvt_pk_bf16_f32 %0, %1, %2" : "=v"(h01) : "v"(p0), "v"(p1));
        asm volatile("v_cvt_pk_bf16_f32 %0, %1, %2" : "=v"(h23) : "v"(p2), "v"(p3));
        const float r0 = p0 - __uint_as_float(h01 << 16);
        const float r1 = p1 - __uint_as_float(h01 & 0xffff0000u);
        const float r2 = p2 - __uint_as_float(h23 << 16);
        const float r3 = p3 - __uint_as_float(h23 & 0xffff0000u);
        unsigned int l01, l23;
        asm volatile("v_cvt_pk_bf16_f32 %0, %1, %2" : "=v"(l01) : "v"(r0), "v"(r1));
        asm volatile("v_cvt_pk_bf16_f32 %0, %1, %2" : "=v"(l23) : "v"(r2), "v"(r3));
        ph.w[u * 2 + 0] = h01;
        ph.w[u * 2 + 1] = h23;
        pl.w[u * 2 + 0] = l01;
        pl.w[u * 2 + 1] = l23;
      }
#pragma unroll
      for (int df = 0; df < 2; df++) {
        oacc[df][f] = __builtin_amdgcn_mfma_f32_16x16x32_bf16(val[df], ph.v, oacc[df][f], 0, 0, 0);
        oacc[df][f] = __builtin_amdgcn_mfma_f32_16x16x32_bf16(vah[df], pl.v, oacc[df][f], 0, 0, 0);
        oacc[df][f] = __builtin_amdgcn_mfma_f32_16x16x32_bf16(vah[df], ph.v, oacc[df][f], 0, 0, 0);
      }
    }
  }

#pragma unroll
  for (int f = 0; f < 2; f++) {
    lacc[f] += __shfl_xor(lacc[f], 16, 64);
    lacc[f] += __shfl_xor(lacc[f], 32, 64);
  }
#pragma unroll
  for (int f = 0; f < 2; f++) {
    const float inv = 1.f / lacc[f];
    const int q = q0 + f * 16 + (lane & 15);
    uint32* op = o + (size_t)(b * S_ + q) * D_ + h * 32;
#pragma unroll
    for (int df = 0; df < 2; df++) {
      const int dbase = df * 16 + (lane >> 4) * 4;
#pragma unroll
      for (int r = 0; r < 4; r++)
        op[dbase + r] = pack_split(oacc[df][f][r] * inv);
    }
  }
}

// ---------------- fused residual + layernorm (fp32 + packed out) ------------
__global__ __launch_bounds__(256) void add_ln(const float* __restrict__ x,
                                              const float* __restrict__ y,
                                              const float* __restrict__ g,
                                              const float* __restrict__ bta,
                                              float* __restrict__ out,
                                              uint32* __restrict__ outp) {
  const int row  = blockIdx.x * 4 + (threadIdx.x >> 6);
  const int lane = threadIdx.x & 63;
  const size_t base = (size_t)row * D_ + lane * 4;
  const float4 xv = *(const float4*)(x + base);
  const float4 yv = *(const float4*)(y + base);
  float v[4] = {xv.x + yv.x, xv.y + yv.y, xv.z + yv.z, xv.w + yv.w};
  float s = v[0] + v[1] + v[2] + v[3];
  s = wave_sum(s);
  const float mean = s * (1.f / 256.f);
  float d[4] = {v[0] - mean, v[1] - mean, v[2] - mean, v[3] - mean};
  float sq = d[0] * d[0] + d[1] * d[1] + d[2] * d[2] + d[3] * d[3];
  sq = wave_sum(sq);
  const float inv = 1.f / sqrtf(sq * (1.f / 256.f) + 1e-5f);
  const float4 gv = *(const float4*)(g + lane * 4);
  const float4 bv = *(const float4*)(bta + lane * 4);
  float4 r;
  r.x = d[0] * inv * gv.x + bv.x; r.y = d[1] * inv * gv.y + bv.y;
  r.z = d[2] * inv * gv.z + bv.z; r.w = d[3] * inv * gv.w + bv.w;
  *(float4*)(out + base) = r;
  uint4 o;
  o.x = pack_split(r.x); o.y = pack_split(r.y);
  o.z = pack_split(r.z); o.w = pack_split(r.w);
  *(uint4*)(outp + base) = o;
}

// ---------------- gate logit -> mask ----------------------------------------
__global__ __launch_bounds__(256) void gate_mask(const float* __restrict__ t,
                                                 const float* __restrict__ Wg2,
                                                 const float* __restrict__ bg2,
                                                 int* __restrict__ mask) {
  const int row  = blockIdx.x * 4 + (threadIdx.x >> 6);
  const int lane = threadIdx.x & 63;
  const float4 tv = *(const float4*)(t + (size_t)row * D_ + lane * 4);
  const float4 wv = *(const float4*)(Wg2 + lane * 4);
  float s = tv.x * wv.x + tv.y * wv.y + tv.z * wv.z + tv.w * wv.w;
  s = wave_sum(s);
  if (lane == 0) mask[row] = (s + bg2[0]) > 0.f ? 1 : 0;
}

// -------- parallel prefix-scan over 16384 masks (sequential semantics) ------
__global__ __launch_bounds__(256) void scan_kernel(const int* __restrict__ mask,
                                                   int* __restrict__ slots,
                                                   int* __restrict__ countp) {
  __shared__ int wtot[4];
  const int tid = threadIdx.x;
  const int lane = tid & 63, wid = tid >> 6;
  const int base = tid * 64;
  int s = 0;
#pragma unroll 8
  for (int i = 0; i < 64; i++) s += mask[base + i];
  int inc = s;
#pragma unroll
  for (int off = 1; off < 64; off <<= 1) {
    const int t = __shfl_up(inc, off, 64);
    if (lane >= off) inc += t;
  }
  if (lane == 63) wtot[wid] = inc;
  __syncthreads();
  int woff = 0;
#pragma unroll
  for (int w = 0; w < 4; w++) woff += (w < wid) ? wtot[w] : 0;
  const int total = wtot[0] + wtot[1] + wtot[2] + wtot[3];
  if (tid == 0) countp[0] = total < M_ ? total : M_;
  int run = woff + inc - s;
  for (int i = 0; i < 64; i++) {
    const int r = base + i;
    const int mk = mask[r];
    slots[r] = (mk && run < M_) ? run : -1;
    run += mk;
  }
}

// ---------------- scatter selected rows into memory -------------------------
__global__ __launch_bounds__(256) void scatter_kernel(const float* __restrict__ h,
                                                      const int* __restrict__ slots,
                                                      float* __restrict__ mem) {
  const int row  = blockIdx.x * 4 + (threadIdx.x >> 6);
  const int lane = threadIdx.x & 63;
  const int sl = slots[row];
  if (sl >= 0)
    *(float4*)(mem + (size_t)sl * D_ + lane * 4) =
        *(const float4*)(h + (size_t)row * D_ + lane * 4);
}

// ---------------- query norms (one wave per batch row) ----------------------
__global__ __launch_bounds__(256) void qnorm_kernel(const float* __restrict__ h,
                                                    float* __restrict__ qden) {
  const int b    = blockIdx.x * 4 + (threadIdx.x >> 6);
  const int lane = threadIdx.x & 63;
  const float4 c = *(const float4*)(h + (size_t)b * S_ * D_ + lane * 4);
  float sq = c.x * c.x + c.y * c.y + c.z * c.z + c.w * c.w;
  sq = wave_sum(sq);
  if (lane == 0) qden[b] = sqrtf(sq) + 1e-8f;
}

// ------- sims[b][r] for all 32 b: one wave per memory row r -----------------
__global__ __launch_bounds__(256) void sims_kernel(const float* __restrict__ h,
                                                   const float* __restrict__ mem,
                                                   const float* __restrict__ qden,
                                                   const int* __restrict__ countp,
                                                   float* __restrict__ sims) {
  __shared__ float cls[B_ * D_];
  __shared__ float qd[B_];
  const int tid = threadIdx.x;
  const int lane = tid & 63, wid = tid >> 6;
  for (int i = tid; i < B_ * D_ / 4; i += 256) {
    const int flat = i * 4;
    const int b = flat >> 8, d = flat & 255;
    *(float4*)&cls[flat] = *(const float4*)(h + (size_t)b * S_ * D_ + d);
  }
  if (tid < B_) qd[tid] = qden[tid];
  __syncthreads();
  const int count = countp[0];
  const int r = blockIdx.x * 4 + wid;
  const float4 m4 = *(const float4*)(mem + (size_t)r * D_ + lane * 4);
  float sq = m4.x * m4.x + m4.y * m4.y + m4.z * m4.z + m4.w * m4.w;
  sq = wave_sum(sq);
  const float rn = sqrtf(sq) + 1e-8f;
  if (r < count) {
    for (int b = 0; b < B_; b++) {
      const float4 c4 = *(const float4*)&cls[b * D_ + lane * 4];
      float dt = m4.x * c4.x + m4.y * c4.y + m4.z * c4.z + m4.w * c4.w;
      dt = wave_sum(dt);
      if (lane == 0) sims[b * M_ + r] = dt / (qd[b] * rn);
    }
  } else if (lane == 0) {
    for (int b = 0; b < B_; b++) sims[b * M_ + r] = -1e9f;
  }
}

// ---------------- per-batch: top-4 (wave-parallel argmax), mix, classifier --
__global__ __launch_bounds__(256) void topk_mix(const float* __restrict__ h,
                                                const float* __restrict__ mem,
                                                const float* __restrict__ simsg,
                                                const int* __restrict__ countp,
                                                const float* __restrict__ Wc,
                                                const float* __restrict__ bc,
                                                float* __restrict__ out) {
  __shared__ float sims[M_];
  __shared__ float cls[D_];
  __shared__ float wv4[4];
  __shared__ int   wi4[4];
  __shared__ float aug[D_];
  __shared__ float tv[4];
  __shared__ int   tix[4];

  const int b = blockIdx.x, tid = threadIdx.x;
  const int lane = tid & 63, wid = tid >> 6;
  const int count = countp[0];

  for (int i = tid; i < M_; i += 256) sims[i] = simsg[b * M_ + i];
  cls[tid] = h[(size_t)b * S_ * D_ + tid];
  __syncthreads();

  for (int k = 0; k < 4; k++) {
    float bv = -INFINITY; int bi = 1 << 30;
#pragma unroll
    for (int rr = 0; rr < M_ / 256; rr++) {
      const int r = tid + rr * 256;
      const float v = sims[r];
      if (v > bv || (v == bv && r < bi)) { bv = v; bi = r; }
    }
#pragma unroll
    for (int off = 1; off < 64; off <<= 1) {
      const float ov = __shfl_xor(bv, off, 64);
      const int   oi = __shfl_xor(bi, off, 64);
      if (ov > bv || (ov == bv && oi < bi)) { bv = ov; bi = oi; }
    }
    if (lane == 0) { wv4[wid] = bv; wi4[wid] = bi; }
    __syncthreads();
    if (tid == 0) {
      float bb = wv4[0]; int bbi = wi4[0];
#pragma unroll
      for (int i = 1; i < 4; i++)
        if (wv4[i] > bb || (wv4[i] == bb && wi4[i] < bbi)) { bb = wv4[i]; bbi = wi4[i]; }
      tv[k] = bb; tix[k] = bbi; sims[bbi] = -INFINITY;
    }
    __syncthreads();
  }

  float w[4];
  {
    const float mx = tv[0];
    float ws = 0.f;
#pragma unroll
    for (int k = 0; k < 4; k++) { w[k] = expf(tv[k] - mx); ws += w[k]; }
    const float inv = 1.f / ws;
#pragma unroll
    for (int k = 0; k < 4; k++) w[k] *= inv;
  }

  {
    float mv = 0.f;
    if (count > 0) {
#pragma unroll
      for (int k = 0; k < 4; k++) mv = fmaf(w[k], mem[(size_t)tix[k] * D_ + tid], mv);
    }
    aug[tid] = cls[tid] + mv;
  }
  __syncthreads();

  const float4 a4 = *(const float4*)&aug[lane * 4];
  for (int c = wid; c < NC_; c += 4) {
    const float4 wc = *(const float4*)(Wc + (size_t)c * D_ + lane * 4);
    float dt = a4.x * wc.x + a4.y * wc.y + a4.z * wc.z + a4.w * wc.w;
    dt = wave_sum(dt);
    if (lane == 0) out[b * NC_ + c] = dt + bc[c];
  }
}

// ---------------- launcher ---------------------------------------------------
extern "C" void kernel_launch(void* const* d_in, const int* in_sizes, int n_in,
                              void* d_out, int out_size, void* d_ws, size_t ws_size,
                              hipStream_t stream) {
  const int*   ids  = (const int*)d_in[0];
  const float* tok  = (const float*)d_in[1];
  const float* pos  = (const float*)d_in[2];
  const float* Wqkv = (const float*)d_in[3];
  const float* bqkv = (const float*)d_in[4];
  const float* Wo   = (const float*)d_in[5];
  const float* bo   = (const float*)d_in[6];
  const float* ln1g = (const float*)d_in[7];
  const float* ln1b = (const float*)d_in[8];
  const float* W1   = (const float*)d_in[9];
  const float* b1   = (const float*)d_in[10];
  const float* W2   = (const float*)d_in[11];
  const float* b2   = (const float*)d_in[12];
  const float* ln2g = (const float*)d_in[13];
  const float* ln2b = (const float*)d_in[14];
  const float* Wg1  = (const float*)d_in[15];
  const float* bg1  = (const float*)d_in[16];
  const float* Wg2  = (const float*)d_in[17];
  const float* bg2  = (const float*)d_in[18];
  const float* Wc   = (const float*)d_in[19];
  const float* bc   = (const float*)d_in[20];
  float* out = (float*)d_out;

  // workspace (all 4-byte words)
  float*  xA    = (float*)d_ws;                    // ROWS*D
  float*  xB    = xA  + (size_t)ROWS * D_;
  float*  pb    = xB  + (size_t)ROWS * D_;
  uint32* xAp   = (uint32*)(pb + (size_t)ROWS * D_);
  uint32* xBp   = xAp + (size_t)ROWS * D_;
  uint32* obp   = xBp + (size_t)ROWS * D_;
  uint32* bigp  = obp + (size_t)ROWS * D_;         // ROWS*FF (QKV 768 / FF1 1024)
  uint32* Wqkvp = bigp + (size_t)ROWS * FF_;       // L*768*256
  uint32* Wop   = Wqkvp + (size_t)L_ * 768 * 256;  // L*256*256
  uint32* W1p   = Wop   + (size_t)L_ * 256 * 256;  // L*1024*256
  uint32* W2p   = W1p   + (size_t)L_ * 1024 * 256; // L*256*1024
  uint32* Wg1p  = W2p   + (size_t)L_ * 256 * 1024; // 256*256
  float*  mem   = (float*)(Wg1p + 256 * 256);
  float*  qden  = mem + (size_t)M_ * D_;
  float*  sims  = qden + 64;
  int*    mask  = (int*)(sims + (size_t)B_ * M_);
  int*    slots = mask + ROWS;
  int*    cnt   = slots + ROWS;

  // pack weights once
  pack_f32<<<(L_ * 768 * 256 / 4 + 255) / 256, 256, 0, stream>>>(Wqkv, Wqkvp, L_ * 768 * 256 / 4);
  pack_f32<<<(L_ * 256 * 256 / 4 + 255) / 256, 256, 0, stream>>>(Wo, Wop, L_ * 256 * 256 / 4);
  pack_f32<<<(L_ * 1024 * 256 / 4 + 255) / 256, 256, 0, stream>>>(W1, W1p, L_ * 1024 * 256 / 4);
  pack_f32<<<(L_ * 256 * 1024 / 4 + 255) / 256, 256, 0, stream>>>(W2, W2p, L_ * 256 * 1024 / 4);
  pack_f32<<<(256 * 256 / 4 + 255) / 256, 256, 0, stream>>>(Wg1, Wg1p, 256 * 256 / 4);

  emb_kernel<<<ROWS / 4, 256, 0, stream>>>(ids, tok, pos, xA, xAp);

  for (int l = 0; l < L_; l++) {
    gemm_mfma<128, 0, 1><<<768, 512, 0, stream>>>(
        xAp, Wqkvp + (size_t)l * 768 * 256, bqkv + l * 768, nullptr, bigp, ROWS, 768, 256, 6);
    attn_mfma<<<B_ * H_, 1024, 0, stream>>>(bigp, obp);
    gemm_mfma<64, 0, 0><<<512, 512, 0, stream>>>(
        obp, Wop + (size_t)l * 256 * 256, bo + l * 256, pb, nullptr, ROWS, 256, 256, 2);
    add_ln<<<ROWS / 4, 256, 0, stream>>>(xA, pb, ln1g + l * 256, ln1b + l * 256, xB, xBp);
    gemm_mfma<128, 1, 1><<<1024, 512, 0, stream>>>(
        xBp, W1p + (size_t)l * 1024 * 256, b1 + l * 1024, nullptr, bigp, ROWS, 1024, 256, 8);
    gemm_mfma<64, 0, 0><<<512, 512, 0, stream>>>(
        bigp, W2p + (size_t)l * 256 * 1024, b2 + l * 256, pb, nullptr, ROWS, 256, 1024, 2);
    add_ln<<<ROWS / 4, 256, 0, stream>>>(xB, pb, ln2g + l * 256, ln2b + l * 256, xA, xAp);
  }

  // gate MLP: t = relu(h @ Wg1^T + bg1) -> mask
  gemm_mfma<64, 1, 0><<<512, 512, 0, stream>>>(
      xAp, Wg1p, bg1, pb, nullptr, ROWS, 256, 256, 2);
  gate_mask<<<ROWS / 4, 256, 0, stream>>>(pb, Wg2, bg2, mask);
  scan_kernel<<<1, 256, 0, stream>>>(mask, slots, cnt);
  (void)hipMemsetAsync(mem, 0, (size_t)M_ * D_ * sizeof(float), stream);
  scatter_kernel<<<ROWS / 4, 256, 0, stream>>>(xA, slots, mem);

  qnorm_kernel<<<B_ / 4, 256, 0, stream>>>(xA, qden);
  sims_kernel<<<M_ / 4, 256, 0, stream>>>(xA, mem, qden, cnt, sims);
  topk_mix<<<B_, 256, 0, stream>>>(xA, mem, sims, cnt, Wc, bc, out);
}

// Round 10
// 423.402 us; speedup vs baseline: 1.1998x; 1.0755x over previous
//
#include <hip/hip_runtime.h>
#include <math.h>

#define D_   256
#define H_   8
#define L_   2
#define FF_  1024
#define S_   512
#define B_   32
#define M_   4096
#define NC_  10
#define ROWS (B_*S_)   // 16384

typedef __attribute__((ext_vector_type(8))) short bf16x8;
typedef __attribute__((ext_vector_type(4))) float f32x4;
typedef unsigned int uint32;

__device__ __forceinline__ float wave_sum(float v) {
#pragma unroll
  for (int off = 1; off < 64; off <<= 1) v += __shfl_xor(v, off, 64);
  return v;
}

__device__ __forceinline__ unsigned short bf16_rne(float x) {
  unsigned int b = __float_as_uint(x);
  return (unsigned short)((b + 0x7FFFu + ((b >> 16) & 1u)) >> 16);
}
__device__ __forceinline__ float bf16_f(unsigned short h) {
  return __uint_as_float(((unsigned int)h) << 16);
}
// split x into hi/lo bf16, packed as hi | (lo<<16)
__device__ __forceinline__ uint32 pack_split(float x) {
  const unsigned short h = bf16_rne(x);
  const unsigned short l = bf16_rne(x - bf16_f(h));
  return (uint32)h | ((uint32)l << 16);
}
// 4 packed elems -> 8B hi-quad + 8B lo-quad into LDS planes
__device__ __forceinline__ void unpack_store(unsigned short* Hq, unsigned short* Lq,
                                             int off, uint4 v) {
  uint2 hp, lp;
  hp.x = (v.x & 0xffffu) | (v.y << 16);
  hp.y = (v.z & 0xffffu) | (v.w << 16);
  lp.x = (v.x >> 16) | (v.y & 0xffff0000u);
  lp.y = (v.z >> 16) | (v.w & 0xffff0000u);
  *(uint2*)&Hq[off] = hp;
  *(uint2*)&Lq[off] = lp;
}
// conflict-free b64-pair fragment load (rows at 72B/1032B stride)
__device__ __forceinline__ bf16x8 ld_frag(const unsigned short* p, int off) {
  union { uint2 u[2]; bf16x8 v; } x;
  x.u[0] = *(const uint2*)(p + off);
  x.u[1] = *(const uint2*)(p + off + 4);
  return x.v;
}

// ---------------- weight packing: fp32 -> packed split (vec4) ---------------
__global__ __launch_bounds__(256) void pack_f32(const float* __restrict__ src,
                                                uint32* __restrict__ dst, int n4) {
  const int i = blockIdx.x * 256 + threadIdx.x;
  if (i < n4) {
    const float4 v = ((const float4*)src)[i];
    uint4 o;
    o.x = pack_split(v.x); o.y = pack_split(v.y);
    o.z = pack_split(v.z); o.w = pack_split(v.w);
    ((uint4*)dst)[i] = o;
  }
}

// ---------------- embedding (fp32 + packed) ---------------------------------
__global__ __launch_bounds__(256) void emb_kernel(const int* __restrict__ ids,
                                                  const float* __restrict__ tok,
                                                  const float* __restrict__ pos,
                                                  float* __restrict__ x,
                                                  uint32* __restrict__ xp) {
  const int row  = blockIdx.x * 4 + (threadIdx.x >> 6);
  const int lane = threadIdx.x & 63;
  const int id = ids[row];
  const int s  = row & (S_ - 1);
  const float4 t = *(const float4*)(tok + (size_t)id * D_ + lane * 4);
  const float4 p = *(const float4*)(pos + (size_t)s  * D_ + lane * 4);
  float4 r; r.x = t.x + p.x; r.y = t.y + p.y; r.z = t.z + p.z; r.w = t.w + p.w;
  *(float4*)(x + (size_t)row * D_ + lane * 4) = r;
  uint4 o;
  o.x = pack_split(r.x); o.y = pack_split(r.y);
  o.z = pack_split(r.z); o.w = pack_split(r.w);
  *(uint4*)(xp + (size_t)row * D_ + lane * 4) = o;
}

// ---- split-bf16 MFMA GEMM, packed operands: C = A*W^T + bias (+ReLU) ------
#define LP 36
template<int BM, int RELU, int PACKOUT>
__global__ __launch_bounds__(512, 4) void gemm_mfma(const uint32* __restrict__ Ap,
                                                    const uint32* __restrict__ Bp,
                                                    const float* __restrict__ bias,
                                                    float* __restrict__ C,
                                                    uint32* __restrict__ Cp,
                                                    int M, int N, int K, int NX) {
  constexpr int WGM = BM / 64;
  constexpr int WGN = 8 / WGM;
  constexpr int WN  = 128 / WGN;
  constexpr int FN  = WN / 16;
  __shared__ __align__(16) unsigned short Ah[BM * LP];
  __shared__ __align__(16) unsigned short Al[BM * LP];
  __shared__ __align__(16) unsigned short Bh[128 * LP];
  __shared__ __align__(16) unsigned short Bl[128 * LP];

  const int q8 = gridDim.x >> 3;
  const int orig = (blockIdx.x & 7) * q8 + (blockIdx.x >> 3);
  const int by = orig / NX, bx = orig % NX;

  const int tid  = threadIdx.x;
  const int lane = tid & 63;
  const int wid  = tid >> 6;
  const int wm = wid / WGN, wn = wid % WGN;
  const int m0 = by * BM, n0 = bx * 128;
  const int lrow  = lane & 15;
  const int khalf = (lane >> 4) * 8;

  const int srow = tid >> 3;            // 0..63 staging row (+j*64)
  const int kq   = (tid & 7) << 2;      // 0,4,..28 k offset
  const uint32* Aptr = Ap + (size_t)(m0 + srow) * K + kq;
  const uint32* Bptr = Bp + (size_t)(n0 + srow) * K + kq;

  f32x4 acc[4][FN];
#pragma unroll
  for (int i = 0; i < 4; i++)
#pragma unroll
    for (int j = 0; j < FN; j++) acc[i][j] = (f32x4){0.f, 0.f, 0.f, 0.f};

  uint4 pa[BM / 64], pb[2];
#pragma unroll
  for (int j = 0; j < BM / 64; j++) pa[j] = *(const uint4*)(Aptr + (size_t)j * 64 * K);
#pragma unroll
  for (int j = 0; j < 2; j++) pb[j] = *(const uint4*)(Bptr + (size_t)j * 64 * K);

  for (int k0 = 0; k0 < K; k0 += 32) {
    const int kn = (k0 + 32 < K) ? (k0 + 32) : k0;
    uint4 na[BM / 64], nb[2];
#pragma unroll
    for (int j = 0; j < BM / 64; j++) na[j] = *(const uint4*)(Aptr + (size_t)j * 64 * K + kn);
#pragma unroll
    for (int j = 0; j < 2; j++) nb[j] = *(const uint4*)(Bptr + (size_t)j * 64 * K + kn);

    __syncthreads();
#pragma unroll
    for (int j = 0; j < BM / 64; j++)
      unpack_store(Ah, Al, (srow + j * 64) * LP + kq, pa[j]);
#pragma unroll
    for (int j = 0; j < 2; j++)
      unpack_store(Bh, Bl, (srow + j * 64) * LP + kq, pb[j]);
    __syncthreads();

    bf16x8 ah[4], al[4], bh[FN], bl[FN];
#pragma unroll
    for (int fm = 0; fm < 4; fm++) {
      const int r = (wm * 64 + fm * 16 + lrow) * LP + khalf;
      ah[fm] = ld_frag(Ah, r);
      al[fm] = ld_frag(Al, r);
    }
#pragma unroll
    for (int fn = 0; fn < FN; fn++) {
      const int r = (wn * WN + fn * 16 + lrow) * LP + khalf;
      bh[fn] = ld_frag(Bh, r);
      bl[fn] = ld_frag(Bl, r);
    }
#pragma unroll
    for (int fm = 0; fm < 4; fm++)
#pragma unroll
      for (int fn = 0; fn < FN; fn++) {
        acc[fm][fn] = __builtin_amdgcn_mfma_f32_16x16x32_bf16(ah[fm], bh[fn], acc[fm][fn], 0, 0, 0);
        acc[fm][fn] = __builtin_amdgcn_mfma_f32_16x16x32_bf16(ah[fm], bl[fn], acc[fm][fn], 0, 0, 0);
        acc[fm][fn] = __builtin_amdgcn_mfma_f32_16x16x32_bf16(al[fm], bh[fn], acc[fm][fn], 0, 0, 0);
      }
#pragma unroll
    for (int j = 0; j < BM / 64; j++) pa[j] = na[j];
#pragma unroll
    for (int j = 0; j < 2; j++) pb[j] = nb[j];
  }

#pragma unroll
  for (int fm = 0; fm < 4; fm++)
#pragma unroll
    for (int fn = 0; fn < FN; fn++) {
      const int mrow = m0 + wm * 64 + fm * 16 + (lane >> 4) * 4;
      const int ncol = n0 + wn * WN + fn * 16 + (lane & 15);
      const float bi = bias[ncol];
#pragma unroll
      for (int r = 0; r < 4; r++) {
        float v = acc[fm][fn][r] + bi;
        if (RELU) v = fmaxf(v, 0.f);
        if (PACKOUT) Cp[(size_t)(mrow + r) * N + ncol] = pack_split(v);
        else         C[(size_t)(mrow + r) * N + ncol] = v;
      }
    }
}

// ---- fused full-row GEMM (N=256): bias + residual + LayerNorm (MODE 0)
//      or bias + ReLU + gate dot (MODE 1). BM=64, BN=256, 1024 thr (16 waves).
template<int MODE>
__global__ __launch_bounds__(1024, 2) void gemm_ln(const uint32* __restrict__ Ap,
                                                   const uint32* __restrict__ Bp,
                                                   const float* __restrict__ bias,
                                                   const float* __restrict__ resid,
                                                   const float* __restrict__ g,
                                                   const float* __restrict__ beta,
                                                   const float* __restrict__ Wg2,
                                                   const float* __restrict__ bg2,
                                                   float* __restrict__ outF,
                                                   uint32* __restrict__ outP,
                                                   int* __restrict__ mask,
                                                   int K) {
  __shared__ __align__(16) unsigned short Ah[64 * LP];
  __shared__ __align__(16) unsigned short Al[64 * LP];
  __shared__ __align__(16) unsigned short Bh[256 * LP];
  __shared__ __align__(16) unsigned short Bl[256 * LP];
  __shared__ float psumS[8][64];
  __shared__ float psumQ[8][64];
  __shared__ float meanL[64];
  __shared__ float invL[64];

  const int q8 = gridDim.x >> 3;
  const int m0 = ((blockIdx.x & 7) * q8 + (blockIdx.x >> 3)) * 64;

  const int tid  = threadIdx.x;
  const int lane = tid & 63;
  const int wid  = tid >> 6;       // 0..15
  const int wm = wid >> 3, wn = wid & 7;
  const int lrow  = lane & 15;
  const int khalf = (lane >> 4) * 8;

  const int srow = tid >> 3;            // 0..127
  const int kq   = (tid & 7) << 2;
  const uint32* Aptr = Ap + (size_t)(m0 + srow) * K + kq;   // valid tid<512
  const uint32* Bptr = Bp + (size_t)srow * K + kq;          // rows srow, srow+128

  f32x4 acc[2][2];
#pragma unroll
  for (int i = 0; i < 2; i++)
#pragma unroll
    for (int j = 0; j < 2; j++) acc[i][j] = (f32x4){0.f, 0.f, 0.f, 0.f};

  uint4 pa, pb0, pb1;
  if (tid < 512) pa = *(const uint4*)Aptr;
  pb0 = *(const uint4*)Bptr;
  pb1 = *(const uint4*)(Bptr + (size_t)128 * K);

  for (int k0 = 0; k0 < K; k0 += 32) {
    const int kn = (k0 + 32 < K) ? (k0 + 32) : k0;
    uint4 na, nb0, nb1;
    if (tid < 512) na = *(const uint4*)(Aptr + kn);
    nb0 = *(const uint4*)(Bptr + kn);
    nb1 = *(const uint4*)(Bptr + (size_t)128 * K + kn);

    __syncthreads();
    if (tid < 512) unpack_store(Ah, Al, srow * LP + kq, pa);
    unpack_store(Bh, Bl, srow * LP + kq, pb0);
    unpack_store(Bh, Bl, (srow + 128) * LP + kq, pb1);
    __syncthreads();

    bf16x8 ah[2], al[2], bh[2], bl[2];
#pragma unroll
    for (int fm = 0; fm < 2; fm++) {
      const int r = (wm * 32 + fm * 16 + lrow) * LP + khalf;
      ah[fm] = ld_frag(Ah, r);
      al[fm] = ld_frag(Al, r);
    }
#pragma unroll
    for (int fn = 0; fn < 2; fn++) {
      const int r = (wn * 32 + fn * 16 + lrow) * LP + khalf;
      bh[fn] = ld_frag(Bh, r);
      bl[fn] = ld_frag(Bl, r);
    }
#pragma unroll
    for (int fm = 0; fm < 2; fm++)
#pragma unroll
      for (int fn = 0; fn < 2; fn++) {
        acc[fm][fn] = __builtin_amdgcn_mfma_f32_16x16x32_bf16(ah[fm], bh[fn], acc[fm][fn], 0, 0, 0);
        acc[fm][fn] = __builtin_amdgcn_mfma_f32_16x16x32_bf16(ah[fm], bl[fn], acc[fm][fn], 0, 0, 0);
        acc[fm][fn] = __builtin_amdgcn_mfma_f32_16x16x32_bf16(al[fm], bh[fn], acc[fm][fn], 0, 0, 0);
      }
    pa = na; pb0 = nb0; pb1 = nb1;
  }

  // ---- epilogue: full row (256 cols) resident in block ----
  const int c0 = wn * 32 + (lane & 15);
  const int c1 = c0 + 16;
  const float b0 = bias[c0], b1 = bias[c1];

  float vv[2][2][4];   // [fm][fn][r]
  float rs[2][4], rq[2][4];

  if (MODE == 0) {
#pragma unroll
    for (int fm = 0; fm < 2; fm++)
#pragma unroll
      for (int r = 0; r < 4; r++) {
        const int row = m0 + wm * 32 + fm * 16 + (lane >> 4) * 4 + r;
        const float x0 = resid[(size_t)row * 256 + c0];
        const float x1 = resid[(size_t)row * 256 + c1];
        const float a = acc[fm][0][r] + b0 + x0;
        const float b = acc[fm][1][r] + b1 + x1;
        vv[fm][0][r] = a; vv[fm][1][r] = b;
        rs[fm][r] = a + b;
        rq[fm][r] = a * a + b * b;
      }
  } else {
    const float w0 = Wg2[c0], w1 = Wg2[c1];
#pragma unroll
    for (int fm = 0; fm < 2; fm++)
#pragma unroll
      for (int r = 0; r < 4; r++) {
        const float a = fmaxf(acc[fm][0][r] + b0, 0.f);
        const float b = fmaxf(acc[fm][1][r] + b1, 0.f);
        rs[fm][r] = a * w0 + b * w1;
      }
  }

#pragma unroll
  for (int off = 1; off < 16; off <<= 1) {
#pragma unroll
    for (int fm = 0; fm < 2; fm++)
#pragma unroll
      for (int r = 0; r < 4; r++) {
        rs[fm][r] += __shfl_xor(rs[fm][r], off, 64);
        if (MODE == 0) rq[fm][r] += __shfl_xor(rq[fm][r], off, 64);
      }
  }
  if ((lane & 15) == 0) {
#pragma unroll
    for (int fm = 0; fm < 2; fm++)
#pragma unroll
      for (int r = 0; r < 4; r++) {
        const int rloc = wm * 32 + fm * 16 + (lane >> 4) * 4 + r;
        psumS[wn][rloc] = rs[fm][r];
        if (MODE == 0) psumQ[wn][rloc] = rq[fm][r];
      }
  }
  __syncthreads();
  if (tid < 64) {
    float s = 0.f, q = 0.f;
#pragma unroll
    for (int w = 0; w < 8; w++) {
      s += psumS[w][tid];
      if (MODE == 0) q += psumQ[w][tid];
    }
    if (MODE == 0) {
      const float mean = s * (1.f / 256.f);
      const float var = q * (1.f / 256.f) - mean * mean;
      meanL[tid] = mean;
      invL[tid] = rsqrtf(var + 1e-5f);
    } else {
      mask[m0 + tid] = (s + bg2[0]) > 0.f ? 1 : 0;
    }
  }
  if (MODE == 0) {
    __syncthreads();
    const float g0 = g[c0], g1 = g[c1];
    const float be0 = beta[c0], be1 = beta[c1];
#pragma unroll
    for (int fm = 0; fm < 2; fm++)
#pragma unroll
      for (int r = 0; r < 4; r++) {
        const int rloc = wm * 32 + fm * 16 + (lane >> 4) * 4 + r;
        const int row = m0 + rloc;
        const float mu = meanL[rloc], iv = invL[rloc];
        const float y0 = (vv[fm][0][r] - mu) * iv * g0 + be0;
        const float y1 = (vv[fm][1][r] - mu) * iv * g1 + be1;
        outF[(size_t)row * 256 + c0] = y0;
        outF[(size_t)row * 256 + c1] = y1;
        outP[(size_t)row * 256 + c0] = pack_split(y0);
        outP[(size_t)row * 256 + c1] = pack_split(y1);
      }
  }
}

// ---------------- MFMA attention (packed in, packed out) --------------------
#define KP 36    // u16/row: 72B stride
#define VP 516   // u16/row: 1032B stride
__global__ __launch_bounds__(1024, 4) void attn_mfma(const uint32* __restrict__ qkv,
                                                     uint32* __restrict__ o) {
  __shared__ __align__(16) unsigned short Kh[512 * KP];
  __shared__ __align__(16) unsigned short Kl[512 * KP];
  __shared__ __align__(16) unsigned short Vth[32 * VP];
  __shared__ __align__(16) unsigned short Vtl[32 * VP];

  const int q8g = gridDim.x >> 3;                 // 32
  const int obh = (blockIdx.x & 7) * q8g + (blockIdx.x >> 3);
  const int b = obh >> 3, h = obh & 7;
  const int tid = threadIdx.x;
  const int lane = tid & 63;
  const int wv = tid >> 6;
  const uint32* base = qkv + (size_t)b * (S_ * 768) + h * 32;

  if (tid < 512) {
    const int slot = tid;
    const int s5 = slot & 31;
    const int orig = (slot & ~31) + 8 * ((s5 >> 2) & 3) + ((s5 >> 4) << 2) + (s5 & 3);
    const uint32* p = base + (size_t)orig * 768 + 256;
#pragma unroll
    for (int j = 0; j < 8; j++)
      unpack_store(Kh, Kl, slot * KP + j * 4, *(const uint4*)(p + j * 4));
  } else {
    const int u  = tid - 512;
    const int kp = u & 255;
    const int dg = (u >> 8) * 16;
    const uint32* p0 = base + (size_t)(2 * kp) * 768 + 512 + dg;
    const uint32* p1 = p0 + 768;
    union { uint4 u4[4]; uint32 w[16]; } a0, a1;
#pragma unroll
    for (int i = 0; i < 4; i++) {
      a0.u4[i] = *(const uint4*)(p0 + i * 4);
      a1.u4[i] = *(const uint4*)(p1 + i * 4);
    }
#pragma unroll
    for (int d = 0; d < 16; d++) {
      const uint32 w0 = a0.w[d], w1 = a1.w[d];
      *(uint32*)&Vth[(dg + d) * VP + 2 * kp] = (w0 & 0xffffu) | (w1 << 16);
      *(uint32*)&Vtl[(dg + d) * VP + 2 * kp] = (w0 >> 16) | (w1 & 0xffff0000u);
    }
  }

  const int q0 = wv * 32;
  bf16x8 qh[2], ql[2];
#pragma unroll
  for (int f = 0; f < 2; f++) {
    const uint32* qp = base + (size_t)(q0 + f * 16 + (lane & 15)) * 768 + ((lane >> 4) * 8);
    union { uint4 u4[2]; uint32 w[8]; } qu;
    qu.u4[0] = *(const uint4*)qp;
    qu.u4[1] = *(const uint4*)(qp + 4);
    bf16x8 vh, vl;
#pragma unroll
    for (int j = 0; j < 8; j++) {
      const uint32 p = qu.w[j];
      const float qf = __uint_as_float(p << 16) + __uint_as_float(p & 0xffff0000u);
      const float sv = qf * 0.17677669529663687f;
      const unsigned short hh = bf16_rne(sv);
      vh[j] = (short)hh;
      vl[j] = (short)bf16_rne(sv - bf16_f(hh));
    }
    qh[f] = vh; ql[f] = vl;
  }

  __syncthreads();

  f32x4 oacc[2][2];
#pragma unroll
  for (int i = 0; i < 2; i++)
#pragma unroll
    for (int j = 0; j < 2; j++) oacc[i][j] = (f32x4){0.f, 0.f, 0.f, 0.f};
  float lacc[2] = {0.f, 0.f};

  for (int kt = 0; kt < S_; kt += 32) {
    bf16x8 kah[2], kal[2];
#pragma unroll
    for (int u = 0; u < 2; u++) {
      const int off = (kt + u * 16 + (lane & 15)) * KP + ((lane >> 4) * 8);
      kah[u] = ld_frag(Kh, off);
      kal[u] = ld_frag(Kl, off);
    }
    bf16x8 vah[2], val[2];
#pragma unroll
    for (int df = 0; df < 2; df++) {
      const int off = (df * 16 + (lane & 15)) * VP + kt + ((lane >> 4) * 8);
      vah[df] = ld_frag(Vth, off);
      val[df] = ld_frag(Vtl, off);
    }
    f32x4 s[2][2];
#pragma unroll
    for (int u = 0; u < 2; u++)
#pragma unroll
      for (int f = 0; f < 2; f++) {
        f32x4 a = (f32x4){0.f, 0.f, 0.f, 0.f};
        a = __builtin_amdgcn_mfma_f32_16x16x32_bf16(kal[u], qh[f], a, 0, 0, 0);
        a = __builtin_amdgcn_mfma_f32_16x16x32_bf16(kah[u], ql[f], a, 0, 0, 0);
        a = __builtin_amdgcn_mfma_f32_16x16x32_bf16(kah[u], qh[f], a, 0, 0, 0);
        s[u][f] = a;
      }
#pragma unroll
    for (int f = 0; f < 2; f++) {
      union { uint32 w[4]; bf16x8 v; } ph, pl;
#pragma unroll
      for (int u = 0; u < 2; u++) {
        const float p0 = __expf(s[u][f][0]);
        const float p1 = __expf(s[u][f][1]);
        const float p2 = __expf(s[u][f][2]);
        const float p3 = __expf(s[u][f][3]);
        lacc[f] += (p0 + p1) + (p2 + p3);
        unsigned int h01, h23;
        asm volatile("v_cvt_pk_bf16_f32 %0, %1, %2" : "=v"(h01) : "v"(p0), "v"(p1));
        asm volatile("v_cvt_pk_bf16_f32 %0, %1, %2" : "=v"(h23) : "v"(p2), "v"(p3));
        const float r0 = p0 - __uint_as_float(h01 << 16);
        const float r1 = p1 - __uint_as_float(h01 & 0xffff0000u);
        const float r2 = p2 - __uint_as_float(h23 << 16);
        const float r3 = p3 - __uint_as_float(h23 & 0xffff0000u);
        unsigned int l01, l23;
        asm volatile("v_cvt_pk_bf16_f32 %0, %1, %2" : "=v"(l01) : "v"(r0), "v"(r1));
        asm volatile("v_cvt_pk_bf16_f32 %0, %1, %2" : "=v"(l23) : "v"(r2), "v"(r3));
        ph.w[u * 2 + 0] = h01;
        ph.w[u * 2 + 1] = h23;
        pl.w[u * 2 + 0] = l01;
        pl.w[u * 2 + 1] = l23;
      }
#pragma unroll
      for (int df = 0; df < 2; df++) {
        oacc[df][f] = __builtin_amdgcn_mfma_f32_16x16x32_bf16(val[df], ph.v, oacc[df][f], 0, 0, 0);
        oacc[df][f] = __builtin_amdgcn_mfma_f32_16x16x32_bf16(vah[df], pl.v, oacc[df][f], 0, 0, 0);
        oacc[df][f] = __builtin_amdgcn_mfma_f32_16x16x32_bf16(vah[df], ph.v, oacc[df][f], 0, 0, 0);
      }
    }
  }

#pragma unroll
  for (int f = 0; f < 2; f++) {
    lacc[f] += __shfl_xor(lacc[f], 16, 64);
    lacc[f] += __shfl_xor(lacc[f], 32, 64);
  }
#pragma unroll
  for (int f = 0; f < 2; f++) {
    const float inv = 1.f / lacc[f];
    const int q = q0 + f * 16 + (lane & 15);
    uint32* op = o + (size_t)(b * S_ + q) * D_ + h * 32;
#pragma unroll
    for (int df = 0; df < 2; df++) {
      const int dbase = df * 16 + (lane >> 4) * 4;
#pragma unroll
      for (int r = 0; r < 4; r++)
        op[dbase + r] = pack_split(oacc[df][f][r] * inv);
    }
  }
}

// -------- parallel prefix-scan over 16384 masks (sequential semantics) ------
__global__ __launch_bounds__(256) void scan_kernel(const int* __restrict__ mask,
                                                   int* __restrict__ slots,
                                                   int* __restrict__ countp) {
  __shared__ int wtot[4];
  const int tid = threadIdx.x;
  const int lane = tid & 63, wid = tid >> 6;
  const int base = tid * 64;
  int s = 0;
#pragma unroll 8
  for (int i = 0; i < 64; i++) s += mask[base + i];
  int inc = s;
#pragma unroll
  for (int off = 1; off < 64; off <<= 1) {
    const int t = __shfl_up(inc, off, 64);
    if (lane >= off) inc += t;
  }
  if (lane == 63) wtot[wid] = inc;
  __syncthreads();
  int woff = 0;
#pragma unroll
  for (int w = 0; w < 4; w++) woff += (w < wid) ? wtot[w] : 0;
  const int total = wtot[0] + wtot[1] + wtot[2] + wtot[3];
  if (tid == 0) countp[0] = total < M_ ? total : M_;
  int run = woff + inc - s;
  for (int i = 0; i < 64; i++) {
    const int r = base + i;
    const int mk = mask[r];
    slots[r] = (mk && run < M_) ? run : -1;
    run += mk;
  }
}

// ---------------- scatter selected rows into memory -------------------------
__global__ __launch_bounds__(256) void scatter_kernel(const float* __restrict__ h,
                                                      const int* __restrict__ slots,
                                                      float* __restrict__ mem) {
  const int row  = blockIdx.x * 4 + (threadIdx.x >> 6);
  const int lane = threadIdx.x & 63;
  const int sl = slots[row];
  if (sl >= 0)
    *(float4*)(mem + (size_t)sl * D_ + lane * 4) =
        *(const float4*)(h + (size_t)row * D_ + lane * 4);
}

// ---------------- query norms (one wave per batch row) ----------------------
__global__ __launch_bounds__(256) void qnorm_kernel(const float* __restrict__ h,
                                                    float* __restrict__ qden) {
  const int b    = blockIdx.x * 4 + (threadIdx.x >> 6);
  const int lane = threadIdx.x & 63;
  const float4 c = *(const float4*)(h + (size_t)b * S_ * D_ + lane * 4);
  float sq = c.x * c.x + c.y * c.y + c.z * c.z + c.w * c.w;
  sq = wave_sum(sq);
  if (lane == 0) qden[b] = sqrtf(sq) + 1e-8f;
}

// ------- sims[b][r] for all 32 b: one wave per memory row r -----------------
__global__ __launch_bounds__(256) void sims_kernel(const float* __restrict__ h,
                                                   const float* __restrict__ mem,
                                                   const float* __restrict__ qden,
                                                   const int* __restrict__ countp,
                                                   float* __restrict__ sims) {
  __shared__ float cls[B_ * D_];
  __shared__ float qd[B_];
  const int tid = threadIdx.x;
  const int lane = tid & 63, wid = tid >> 6;
  for (int i = tid; i < B_ * D_ / 4; i += 256) {
    const int flat = i * 4;
    const int b = flat >> 8, d = flat & 255;
    *(float4*)&cls[flat] = *(const float4*)(h + (size_t)b * S_ * D_ + d);
  }
  if (tid < B_) qd[tid] = qden[tid];
  __syncthreads();
  const int count = countp[0];
  const int r = blockIdx.x * 4 + wid;
  const float4 m4 = *(const float4*)(mem + (size_t)r * D_ + lane * 4);
  float sq = m4.x * m4.x + m4.y * m4.y + m4.z * m4.z + m4.w * m4.w;
  sq = wave_sum(sq);
  const float rn = sqrtf(sq) + 1e-8f;
  if (r < count) {
    for (int b = 0; b < B_; b++) {
      const float4 c4 = *(const float4*)&cls[b * D_ + lane * 4];
      float dt = m4.x * c4.x + m4.y * c4.y + m4.z * c4.z + m4.w * c4.w;
      dt = wave_sum(dt);
      if (lane == 0) sims[b * M_ + r] = dt / (qd[b] * rn);
    }
  } else if (lane == 0) {
    for (int b = 0; b < B_; b++) sims[b * M_ + r] = -1e9f;
  }
}

// ---------------- per-batch: top-4 (wave-parallel argmax), mix, classifier --
__global__ __launch_bounds__(256) void topk_mix(const float* __restrict__ h,
                                                const float* __restrict__ mem,
                                                const float* __restrict__ simsg,
                                                const int* __restrict__ countp,
                                                const float* __restrict__ Wc,
                                                const float* __restrict__ bc,
                                                float* __restrict__ out) {
  __shared__ float sims[M_];
  __shared__ float cls[D_];
  __shared__ float wv4[4];
  __shared__ int   wi4[4];
  __shared__ float aug[D_];
  __shared__ float tv[4];
  __shared__ int   tix[4];

  const int b = blockIdx.x, tid = threadIdx.x;
  const int lane = tid & 63, wid = tid >> 6;
  const int count = countp[0];

  for (int i = tid; i < M_; i += 256) sims[i] = simsg[b * M_ + i];
  cls[tid] = h[(size_t)b * S_ * D_ + tid];
  __syncthreads();

  for (int k = 0; k < 4; k++) {
    float bv = -INFINITY; int bi = 1 << 30;
#pragma unroll
    for (int rr = 0; rr < M_ / 256; rr++) {
      const int r = tid + rr * 256;
      const float v = sims[r];
      if (v > bv || (v == bv && r < bi)) { bv = v; bi = r; }
    }
#pragma unroll
    for (int off = 1; off < 64; off <<= 1) {
      const float ov = __shfl_xor(bv, off, 64);
      const int   oi = __shfl_xor(bi, off, 64);
      if (ov > bv || (ov == bv && oi < bi)) { bv = ov; bi = oi; }
    }
    if (lane == 0) { wv4[wid] = bv; wi4[wid] = bi; }
    __syncthreads();
    if (tid == 0) {
      float bb = wv4[0]; int bbi = wi4[0];
#pragma unroll
      for (int i = 1; i < 4; i++)
        if (wv4[i] > bb || (wv4[i] == bb && wi4[i] < bbi)) { bb = wv4[i]; bbi = wi4[i]; }
      tv[k] = bb; tix[k] = bbi; sims[bbi] = -INFINITY;
    }
    __syncthreads();
  }

  float w[4];
  {
    const float mx = tv[0];
    float ws = 0.f;
#pragma unroll
    for (int k = 0; k < 4; k++) { w[k] = expf(tv[k] - mx); ws += w[k]; }
    const float inv = 1.f / ws;
#pragma unroll
    for (int k = 0; k < 4; k++) w[k] *= inv;
  }

  {
    float mv = 0.f;
    if (count > 0) {
#pragma unroll
      for (int k = 0; k < 4; k++) mv = fmaf(w[k], mem[(size_t)tix[k] * D_ + tid], mv);
    }
    aug[tid] = cls[tid] + mv;
  }
  __syncthreads();

  const float4 a4 = *(const float4*)&aug[lane * 4];
  for (int c = wid; c < NC_; c += 4) {
    const float4 wc = *(const float4*)(Wc + (size_t)c * D_ + lane * 4);
    float dt = a4.x * wc.x + a4.y * wc.y + a4.z * wc.z + a4.w * wc.w;
    dt = wave_sum(dt);
    if (lane == 0) out[b * NC_ + c] = dt + bc[c];
  }
}

// ---------------- launcher ---------------------------------------------------
extern "C" void kernel_launch(void* const* d_in, const int* in_sizes, int n_in,
                              void* d_out, int out_size, void* d_ws, size_t ws_size,
                              hipStream_t stream) {
  const int*   ids  = (const int*)d_in[0];
  const float* tok  = (const float*)d_in[1];
  const float* pos  = (const float*)d_in[2];
  const float* Wqkv = (const float*)d_in[3];
  const float* bqkv = (const float*)d_in[4];
  const float* Wo   = (const float*)d_in[5];
  const float* bo   = (const float*)d_in[6];
  const float* ln1g = (const float*)d_in[7];
  const float* ln1b = (const float*)d_in[8];
  const float* W1   = (const float*)d_in[9];
  const float* b1   = (const float*)d_in[10];
  const float* W2   = (const float*)d_in[11];
  const float* b2   = (const float*)d_in[12];
  const float* ln2g = (const float*)d_in[13];
  const float* ln2b = (const float*)d_in[14];
  const float* Wg1  = (const float*)d_in[15];
  const float* bg1  = (const float*)d_in[16];
  const float* Wg2  = (const float*)d_in[17];
  const float* bg2  = (const float*)d_in[18];
  const float* Wc   = (const float*)d_in[19];
  const float* bc   = (const float*)d_in[20];
  float* out = (float*)d_out;

  // workspace (all 4-byte words)
  float*  xA    = (float*)d_ws;                    // ROWS*D
  float*  xB    = xA  + (size_t)ROWS * D_;
  uint32* xAp   = (uint32*)(xB + (size_t)ROWS * D_);
  uint32* xBp   = xAp + (size_t)ROWS * D_;
  uint32* obp   = xBp + (size_t)ROWS * D_;
  uint32* bigp  = obp + (size_t)ROWS * D_;         // ROWS*FF (QKV 768 / FF1 1024)
  uint32* Wqkvp = bigp + (size_t)ROWS * FF_;       // L*768*256
  uint32* Wop   = Wqkvp + (size_t)L_ * 768 * 256;  // L*256*256
  uint32* W1p   = Wop   + (size_t)L_ * 256 * 256;  // L*1024*256
  uint32* W2p   = W1p   + (size_t)L_ * 1024 * 256; // L*256*1024
  uint32* Wg1p  = W2p   + (size_t)L_ * 256 * 1024; // 256*256
  float*  mem   = (float*)(Wg1p + 256 * 256);
  float*  qden  = mem + (size_t)M_ * D_;
  float*  sims  = qden + 64;
  int*    mask  = (int*)(sims + (size_t)B_ * M_);
  int*    slots = mask + ROWS;
  int*    cnt   = slots + ROWS;

  // pack weights once
  pack_f32<<<(L_ * 768 * 256 / 4 + 255) / 256, 256, 0, stream>>>(Wqkv, Wqkvp, L_ * 768 * 256 / 4);
  pack_f32<<<(L_ * 256 * 256 / 4 + 255) / 256, 256, 0, stream>>>(Wo, Wop, L_ * 256 * 256 / 4);
  pack_f32<<<(L_ * 1024 * 256 / 4 + 255) / 256, 256, 0, stream>>>(W1, W1p, L_ * 1024 * 256 / 4);
  pack_f32<<<(L_ * 256 * 1024 / 4 + 255) / 256, 256, 0, stream>>>(W2, W2p, L_ * 256 * 1024 / 4);
  pack_f32<<<(256 * 256 / 4 + 255) / 256, 256, 0, stream>>>(Wg1, Wg1p, 256 * 256 / 4);

  emb_kernel<<<ROWS / 4, 256, 0, stream>>>(ids, tok, pos, xA, xAp);

  for (int l = 0; l < L_; l++) {
    gemm_mfma<128, 0, 1><<<768, 512, 0, stream>>>(
        xAp, Wqkvp + (size_t)l * 768 * 256, bqkv + l * 768, nullptr, bigp, ROWS, 768, 256, 6);
    attn_mfma<<<B_ * H_, 1024, 0, stream>>>(bigp, obp);
    // Wo GEMM fused with residual(xA) + LN1 -> xB (fp32 + packed)
    gemm_ln<0><<<ROWS / 64, 1024, 0, stream>>>(
        obp, Wop + (size_t)l * 256 * 256, bo + l * 256, xA,
        ln1g + l * 256, ln1b + l * 256, nullptr, nullptr, xB, xBp, nullptr, 256);
    gemm_mfma<128, 1, 1><<<1024, 512, 0, stream>>>(
        xBp, W1p + (size_t)l * 1024 * 256, b1 + l * 1024, nullptr, bigp, ROWS, 1024, 256, 8);
    // W2 GEMM fused with residual(xB) + LN2 -> xA (fp32 + packed)
    gemm_ln<0><<<ROWS / 64, 1024, 0, stream>>>(
        bigp, W2p + (size_t)l * 256 * 1024, b2 + l * 256, xB,
        ln2g + l * 256, ln2b + l * 256, nullptr, nullptr, xA, xAp, nullptr, 1024);
  }

  // gate MLP fused: mask[row] = (relu(h@Wg1^T+bg1) . Wg2 + bg2) > 0
  gemm_ln<1><<<ROWS / 64, 1024, 0, stream>>>(
      xAp, Wg1p, bg1, nullptr, nullptr, nullptr, Wg2, bg2, nullptr, nullptr, mask, 256);
  scan_kernel<<<1, 256, 0, stream>>>(mask, slots, cnt);
  (void)hipMemsetAsync(mem, 0, (size_t)M_ * D_ * sizeof(float), stream);
  scatter_kernel<<<ROWS / 4, 256, 0, stream>>>(xA, slots, mem);

  qnorm_kernel<<<B_ / 4, 256, 0, stream>>>(xA, qden);
  sims_kernel<<<M_ / 4, 256, 0, stream>>>(xA, mem, qden, cnt, sims);
  topk_mix<<<B_, 256, 0, stream>>>(xA, mem, sims, cnt, Wc, bc, out);
}

// Round 11
// 417.591 us; speedup vs baseline: 1.2165x; 1.0139x over previous
//
#include <hip/hip_runtime.h>
#include <math.h>

#define D_   256
#define H_   8
#define L_   2
#define FF_  1024
#define S_   512
#define B_   32
#define M_   4096
#define NC_  10
#define ROWS (B_*S_)   // 16384

typedef __attribute__((ext_vector_type(8))) short bf16x8;
typedef __attribute__((ext_vector_type(4))) float f32x4;
typedef unsigned int uint32;

__device__ __forceinline__ float wave_sum(float v) {
#pragma unroll
  for (int off = 1; off < 64; off <<= 1) v += __shfl_xor(v, off, 64);
  return v;
}

__device__ __forceinline__ unsigned short bf16_rne(float x) {
  unsigned int b = __float_as_uint(x);
  return (unsigned short)((b + 0x7FFFu + ((b >> 16) & 1u)) >> 16);
}
__device__ __forceinline__ float bf16_f(unsigned short h) {
  return __uint_as_float(((unsigned int)h) << 16);
}
// split x into hi/lo bf16, packed as hi | (lo<<16)
__device__ __forceinline__ uint32 pack_split(float x) {
  const unsigned short h = bf16_rne(x);
  const unsigned short l = bf16_rne(x - bf16_f(h));
  return (uint32)h | ((uint32)l << 16);
}
// 4 packed elems -> 8B hi-quad + 8B lo-quad into LDS planes
__device__ __forceinline__ void unpack_store(unsigned short* Hq, unsigned short* Lq,
                                             int off, uint4 v) {
  uint2 hp, lp;
  hp.x = (v.x & 0xffffu) | (v.y << 16);
  hp.y = (v.z & 0xffffu) | (v.w << 16);
  lp.x = (v.x >> 16) | (v.y & 0xffff0000u);
  lp.y = (v.z >> 16) | (v.w & 0xffff0000u);
  *(uint2*)&Hq[off] = hp;
  *(uint2*)&Lq[off] = lp;
}
// conflict-free b64-pair fragment load (rows at 72B/1032B stride)
__device__ __forceinline__ bf16x8 ld_frag(const unsigned short* p, int off) {
  union { uint2 u[2]; bf16x8 v; } x;
  x.u[0] = *(const uint2*)(p + off);
  x.u[1] = *(const uint2*)(p + off + 4);
  return x.v;
}

// ---------------- weight packing: fp32 -> packed split (vec4) ---------------
__global__ __launch_bounds__(256) void pack_f32(const float* __restrict__ src,
                                                uint32* __restrict__ dst, int n4) {
  const int i = blockIdx.x * 256 + threadIdx.x;
  if (i < n4) {
    const float4 v = ((const float4*)src)[i];
    uint4 o;
    o.x = pack_split(v.x); o.y = pack_split(v.y);
    o.z = pack_split(v.z); o.w = pack_split(v.w);
    ((uint4*)dst)[i] = o;
  }
}

// ---------------- embedding (fp32 + packed) ---------------------------------
__global__ __launch_bounds__(256) void emb_kernel(const int* __restrict__ ids,
                                                  const float* __restrict__ tok,
                                                  const float* __restrict__ pos,
                                                  float* __restrict__ x,
                                                  uint32* __restrict__ xp) {
  const int row  = blockIdx.x * 4 + (threadIdx.x >> 6);
  const int lane = threadIdx.x & 63;
  const int id = ids[row];
  const int s  = row & (S_ - 1);
  const float4 t = *(const float4*)(tok + (size_t)id * D_ + lane * 4);
  const float4 p = *(const float4*)(pos + (size_t)s  * D_ + lane * 4);
  float4 r; r.x = t.x + p.x; r.y = t.y + p.y; r.z = t.z + p.z; r.w = t.w + p.w;
  *(float4*)(x + (size_t)row * D_ + lane * 4) = r;
  uint4 o;
  o.x = pack_split(r.x); o.y = pack_split(r.y);
  o.z = pack_split(r.z); o.w = pack_split(r.w);
  *(uint4*)(xp + (size_t)row * D_ + lane * 4) = o;
}

// ---- split-bf16 MFMA GEMM v2: 128x128 block, 4 waves of 64x64 -------------
// 48 FLOP per LDS byte -> MFMA-bound. 2 blocks/CU overlap staging/compute.
#define LP 36
template<int RELU, int PACKOUT>
__global__ __launch_bounds__(256, 2) void gemm_mfma(const uint32* __restrict__ Ap,
                                                    const uint32* __restrict__ Bp,
                                                    const float* __restrict__ bias,
                                                    float* __restrict__ C,
                                                    uint32* __restrict__ Cp,
                                                    int K, int N, int NX) {
  __shared__ __align__(16) unsigned short Ah[128 * LP];
  __shared__ __align__(16) unsigned short Al[128 * LP];
  __shared__ __align__(16) unsigned short Bh[128 * LP];
  __shared__ __align__(16) unsigned short Bl[128 * LP];

  const int q8 = gridDim.x >> 3;
  const int orig = (blockIdx.x & 7) * q8 + (blockIdx.x >> 3);
  const int by = orig / NX, bx = orig % NX;
  const int m0 = by * 128, n0 = bx * 128;

  const int tid  = threadIdx.x;
  const int lane = tid & 63;
  const int wid  = tid >> 6;        // 0..3
  const int wm = wid >> 1, wn = wid & 1;
  const int lrow  = lane & 15;
  const int khalf = (lane >> 4) * 8;

  const int srow = tid >> 3;        // 0..31 (+j*32)
  const int kq   = (tid & 7) << 2;
  const uint32* Aptr = Ap + (size_t)(m0 + srow) * K + kq;
  const uint32* Bptr = Bp + (size_t)(n0 + srow) * K + kq;

  f32x4 acc[4][4];
#pragma unroll
  for (int i = 0; i < 4; i++)
#pragma unroll
    for (int j = 0; j < 4; j++) acc[i][j] = (f32x4){0.f, 0.f, 0.f, 0.f};

  uint4 pa[4], pb[4];
#pragma unroll
  for (int j = 0; j < 4; j++) {
    pa[j] = *(const uint4*)(Aptr + (size_t)j * 32 * K);
    pb[j] = *(const uint4*)(Bptr + (size_t)j * 32 * K);
  }

  for (int k0 = 0; k0 < K; k0 += 32) {
    const int kn = (k0 + 32 < K) ? (k0 + 32) : k0;
    uint4 na[4], nb[4];
#pragma unroll
    for (int j = 0; j < 4; j++) {
      na[j] = *(const uint4*)(Aptr + (size_t)j * 32 * K + kn);
      nb[j] = *(const uint4*)(Bptr + (size_t)j * 32 * K + kn);
    }

    __syncthreads();
#pragma unroll
    for (int j = 0; j < 4; j++) {
      unpack_store(Ah, Al, (srow + j * 32) * LP + kq, pa[j]);
      unpack_store(Bh, Bl, (srow + j * 32) * LP + kq, pb[j]);
    }
    __syncthreads();

    bf16x8 ah[4], al[4], bh[4], bl[4];
#pragma unroll
    for (int f = 0; f < 4; f++) {
      const int rA = (wm * 64 + f * 16 + lrow) * LP + khalf;
      const int rB = (wn * 64 + f * 16 + lrow) * LP + khalf;
      ah[f] = ld_frag(Ah, rA);
      al[f] = ld_frag(Al, rA);
      bh[f] = ld_frag(Bh, rB);
      bl[f] = ld_frag(Bl, rB);
    }
#pragma unroll
    for (int fm = 0; fm < 4; fm++)
#pragma unroll
      for (int fn = 0; fn < 4; fn++) {
        acc[fm][fn] = __builtin_amdgcn_mfma_f32_16x16x32_bf16(ah[fm], bh[fn], acc[fm][fn], 0, 0, 0);
        acc[fm][fn] = __builtin_amdgcn_mfma_f32_16x16x32_bf16(ah[fm], bl[fn], acc[fm][fn], 0, 0, 0);
        acc[fm][fn] = __builtin_amdgcn_mfma_f32_16x16x32_bf16(al[fm], bh[fn], acc[fm][fn], 0, 0, 0);
      }
#pragma unroll
    for (int j = 0; j < 4; j++) { pa[j] = na[j]; pb[j] = nb[j]; }
  }

#pragma unroll
  for (int fm = 0; fm < 4; fm++)
#pragma unroll
    for (int fn = 0; fn < 4; fn++) {
      const int mrow = m0 + wm * 64 + fm * 16 + (lane >> 4) * 4;
      const int ncol = n0 + wn * 64 + fn * 16 + (lane & 15);
      const float bi = bias[ncol];
#pragma unroll
      for (int r = 0; r < 4; r++) {
        float v = acc[fm][fn][r] + bi;
        if (RELU) v = fmaxf(v, 0.f);
        if (PACKOUT) Cp[(size_t)(mrow + r) * N + ncol] = pack_split(v);
        else         C[(size_t)(mrow + r) * N + ncol] = v;
      }
    }
}

// ---- fused full-row GEMM v2 (N=256): 64x256 block, 8 waves of 32x64 -------
// MODE 0: bias + residual + LayerNorm; MODE 1: bias + ReLU + gate dot.
template<int MODE>
__global__ __launch_bounds__(512, 2) void gemm_ln(const uint32* __restrict__ Ap,
                                                  const uint32* __restrict__ Bp,
                                                  const float* __restrict__ bias,
                                                  const float* __restrict__ resid,
                                                  const float* __restrict__ g,
                                                  const float* __restrict__ beta,
                                                  const float* __restrict__ Wg2,
                                                  const float* __restrict__ bg2,
                                                  float* __restrict__ outF,
                                                  uint32* __restrict__ outP,
                                                  int* __restrict__ mask,
                                                  int K) {
  __shared__ __align__(16) unsigned short Ah[64 * LP];
  __shared__ __align__(16) unsigned short Al[64 * LP];
  __shared__ __align__(16) unsigned short Bh[256 * LP];
  __shared__ __align__(16) unsigned short Bl[256 * LP];
  __shared__ float psumS[4][64];
  __shared__ float psumQ[4][64];
  __shared__ float meanL[64];
  __shared__ float invL[64];

  const int q8 = gridDim.x >> 3;
  const int m0 = ((blockIdx.x & 7) * q8 + (blockIdx.x >> 3)) * 64;

  const int tid  = threadIdx.x;
  const int lane = tid & 63;
  const int wid  = tid >> 6;       // 0..7
  const int wm = wid >> 2, wn = wid & 3;
  const int lrow  = lane & 15;
  const int khalf = (lane >> 4) * 8;

  const int srow = tid >> 3;            // 0..63
  const int kq   = (tid & 7) << 2;
  const uint32* Aptr = Ap + (size_t)(m0 + srow) * K + kq;
  const uint32* Bptr = Bp + (size_t)srow * K + kq;    // rows srow + j*64

  f32x4 acc[2][4];
#pragma unroll
  for (int i = 0; i < 2; i++)
#pragma unroll
    for (int j = 0; j < 4; j++) acc[i][j] = (f32x4){0.f, 0.f, 0.f, 0.f};

  uint4 pa, pb[4];
  pa = *(const uint4*)Aptr;
#pragma unroll
  for (int j = 0; j < 4; j++) pb[j] = *(const uint4*)(Bptr + (size_t)j * 64 * K);

  for (int k0 = 0; k0 < K; k0 += 32) {
    const int kn = (k0 + 32 < K) ? (k0 + 32) : k0;
    uint4 na, nb[4];
    na = *(const uint4*)(Aptr + kn);
#pragma unroll
    for (int j = 0; j < 4; j++) nb[j] = *(const uint4*)(Bptr + (size_t)j * 64 * K + kn);

    __syncthreads();
    unpack_store(Ah, Al, srow * LP + kq, pa);
#pragma unroll
    for (int j = 0; j < 4; j++)
      unpack_store(Bh, Bl, (srow + j * 64) * LP + kq, pb[j]);
    __syncthreads();

    bf16x8 ah[2], al[2], bh[4], bl[4];
#pragma unroll
    for (int fm = 0; fm < 2; fm++) {
      const int r = (wm * 32 + fm * 16 + lrow) * LP + khalf;
      ah[fm] = ld_frag(Ah, r);
      al[fm] = ld_frag(Al, r);
    }
#pragma unroll
    for (int fn = 0; fn < 4; fn++) {
      const int r = (wn * 64 + fn * 16 + lrow) * LP + khalf;
      bh[fn] = ld_frag(Bh, r);
      bl[fn] = ld_frag(Bl, r);
    }
#pragma unroll
    for (int fm = 0; fm < 2; fm++)
#pragma unroll
      for (int fn = 0; fn < 4; fn++) {
        acc[fm][fn] = __builtin_amdgcn_mfma_f32_16x16x32_bf16(ah[fm], bh[fn], acc[fm][fn], 0, 0, 0);
        acc[fm][fn] = __builtin_amdgcn_mfma_f32_16x16x32_bf16(ah[fm], bl[fn], acc[fm][fn], 0, 0, 0);
        acc[fm][fn] = __builtin_amdgcn_mfma_f32_16x16x32_bf16(al[fm], bh[fn], acc[fm][fn], 0, 0, 0);
      }
    pa = na;
#pragma unroll
    for (int j = 0; j < 4; j++) pb[j] = nb[j];
  }

  // ---- epilogue: full row (256 cols) resident in block ----
  int cc[4];
  float bi[4];
#pragma unroll
  for (int fn = 0; fn < 4; fn++) {
    cc[fn] = wn * 64 + fn * 16 + (lane & 15);
    bi[fn] = bias[cc[fn]];
  }

  float vv[2][4][4];
  float rs[2][4], rq[2][4];

  if (MODE == 0) {
#pragma unroll
    for (int fm = 0; fm < 2; fm++)
#pragma unroll
      for (int r = 0; r < 4; r++) {
        const int row = m0 + wm * 32 + fm * 16 + (lane >> 4) * 4 + r;
        float s = 0.f, q = 0.f;
#pragma unroll
        for (int fn = 0; fn < 4; fn++) {
          const float a = acc[fm][fn][r] + bi[fn] + resid[(size_t)row * 256 + cc[fn]];
          vv[fm][fn][r] = a;
          s += a; q += a * a;
        }
        rs[fm][r] = s; rq[fm][r] = q;
      }
  } else {
    float wg[4];
#pragma unroll
    for (int fn = 0; fn < 4; fn++) wg[fn] = Wg2[cc[fn]];
#pragma unroll
    for (int fm = 0; fm < 2; fm++)
#pragma unroll
      for (int r = 0; r < 4; r++) {
        float s = 0.f;
#pragma unroll
        for (int fn = 0; fn < 4; fn++)
          s += fmaxf(acc[fm][fn][r] + bi[fn], 0.f) * wg[fn];
        rs[fm][r] = s;
      }
  }

#pragma unroll
  for (int off = 1; off < 16; off <<= 1) {
#pragma unroll
    for (int fm = 0; fm < 2; fm++)
#pragma unroll
      for (int r = 0; r < 4; r++) {
        rs[fm][r] += __shfl_xor(rs[fm][r], off, 64);
        if (MODE == 0) rq[fm][r] += __shfl_xor(rq[fm][r], off, 64);
      }
  }
  if ((lane & 15) == 0) {
#pragma unroll
    for (int fm = 0; fm < 2; fm++)
#pragma unroll
      for (int r = 0; r < 4; r++) {
        const int rloc = wm * 32 + fm * 16 + (lane >> 4) * 4 + r;
        psumS[wn][rloc] = rs[fm][r];
        if (MODE == 0) psumQ[wn][rloc] = rq[fm][r];
      }
  }
  __syncthreads();
  if (tid < 64) {
    float s = 0.f, q = 0.f;
#pragma unroll
    for (int w = 0; w < 4; w++) {
      s += psumS[w][tid];
      if (MODE == 0) q += psumQ[w][tid];
    }
    if (MODE == 0) {
      const float mean = s * (1.f / 256.f);
      const float var = q * (1.f / 256.f) - mean * mean;
      meanL[tid] = mean;
      invL[tid] = rsqrtf(var + 1e-5f);
    } else {
      mask[m0 + tid] = (s + bg2[0]) > 0.f ? 1 : 0;
    }
  }
  if (MODE == 0) {
    __syncthreads();
#pragma unroll
    for (int fm = 0; fm < 2; fm++)
#pragma unroll
      for (int r = 0; r < 4; r++) {
        const int rloc = wm * 32 + fm * 16 + (lane >> 4) * 4 + r;
        const int row = m0 + rloc;
        const float mu = meanL[rloc], iv = invL[rloc];
#pragma unroll
        for (int fn = 0; fn < 4; fn++) {
          const float y = (vv[fm][fn][r] - mu) * iv * g[cc[fn]] + beta[cc[fn]];
          outF[(size_t)row * 256 + cc[fn]] = y;
          outP[(size_t)row * 256 + cc[fn]] = pack_split(y);
        }
      }
  }
}

// ---------------- MFMA attention (packed in, packed out) --------------------
#define KP 36    // u16/row: 72B stride
#define VP 516   // u16/row: 1032B stride
__global__ __launch_bounds__(1024, 4) void attn_mfma(const uint32* __restrict__ qkv,
                                                     uint32* __restrict__ o) {
  __shared__ __align__(16) unsigned short Kh[512 * KP];
  __shared__ __align__(16) unsigned short Kl[512 * KP];
  __shared__ __align__(16) unsigned short Vth[32 * VP];
  __shared__ __align__(16) unsigned short Vtl[32 * VP];

  const int q8g = gridDim.x >> 3;                 // 32
  const int obh = (blockIdx.x & 7) * q8g + (blockIdx.x >> 3);
  const int b = obh >> 3, h = obh & 7;
  const int tid = threadIdx.x;
  const int lane = tid & 63;
  const int wv = tid >> 6;
  const uint32* base = qkv + (size_t)b * (S_ * 768) + h * 32;

  if (tid < 512) {
    const int slot = tid;
    const int s5 = slot & 31;
    const int orig = (slot & ~31) + 8 * ((s5 >> 2) & 3) + ((s5 >> 4) << 2) + (s5 & 3);
    const uint32* p = base + (size_t)orig * 768 + 256;
#pragma unroll
    for (int j = 0; j < 8; j++)
      unpack_store(Kh, Kl, slot * KP + j * 4, *(const uint4*)(p + j * 4));
  } else {
    const int u  = tid - 512;
    const int kp = u & 255;
    const int dg = (u >> 8) * 16;
    const uint32* p0 = base + (size_t)(2 * kp) * 768 + 512 + dg;
    const uint32* p1 = p0 + 768;
    union { uint4 u4[4]; uint32 w[16]; } a0, a1;
#pragma unroll
    for (int i = 0; i < 4; i++) {
      a0.u4[i] = *(const uint4*)(p0 + i * 4);
      a1.u4[i] = *(const uint4*)(p1 + i * 4);
    }
#pragma unroll
    for (int d = 0; d < 16; d++) {
      const uint32 w0 = a0.w[d], w1 = a1.w[d];
      *(uint32*)&Vth[(dg + d) * VP + 2 * kp] = (w0 & 0xffffu) | (w1 << 16);
      *(uint32*)&Vtl[(dg + d) * VP + 2 * kp] = (w0 >> 16) | (w1 & 0xffff0000u);
    }
  }

  const int q0 = wv * 32;
  bf16x8 qh[2], ql[2];
#pragma unroll
  for (int f = 0; f < 2; f++) {
    const uint32* qp = base + (size_t)(q0 + f * 16 + (lane & 15)) * 768 + ((lane >> 4) * 8);
    union { uint4 u4[2]; uint32 w[8]; } qu;
    qu.u4[0] = *(const uint4*)qp;
    qu.u4[1] = *(const uint4*)(qp + 4);
    bf16x8 vh, vl;
#pragma unroll
    for (int j = 0; j < 8; j++) {
      const uint32 p = qu.w[j];
      const float qf = __uint_as_float(p << 16) + __uint_as_float(p & 0xffff0000u);
      const float sv = qf * 0.17677669529663687f;
      const unsigned short hh = bf16_rne(sv);
      vh[j] = (short)hh;
      vl[j] = (short)bf16_rne(sv - bf16_f(hh));
    }
    qh[f] = vh; ql[f] = vl;
  }

  __syncthreads();

  f32x4 oacc[2][2];
#pragma unroll
  for (int i = 0; i < 2; i++)
#pragma unroll
    for (int j = 0; j < 2; j++) oacc[i][j] = (f32x4){0.f, 0.f, 0.f, 0.f};
  float lacc[2] = {0.f, 0.f};

  for (int kt = 0; kt < S_; kt += 32) {
    bf16x8 kah[2], kal[2];
#pragma unroll
    for (int u = 0; u < 2; u++) {
      const int off = (kt + u * 16 + (lane & 15)) * KP + ((lane >> 4) * 8);
      kah[u] = ld_frag(Kh, off);
      kal[u] = ld_frag(Kl, off);
    }
    bf16x8 vah[2], val[2];
#pragma unroll
    for (int df = 0; df < 2; df++) {
      const int off = (df * 16 + (lane & 15)) * VP + kt + ((lane >> 4) * 8);
      vah[df] = ld_frag(Vth, off);
      val[df] = ld_frag(Vtl, off);
    }
    f32x4 s[2][2];
#pragma unroll
    for (int u = 0; u < 2; u++)
#pragma unroll
      for (int f = 0; f < 2; f++) {
        f32x4 a = (f32x4){0.f, 0.f, 0.f, 0.f};
        a = __builtin_amdgcn_mfma_f32_16x16x32_bf16(kal[u], qh[f], a, 0, 0, 0);
        a = __builtin_amdgcn_mfma_f32_16x16x32_bf16(kah[u], ql[f], a, 0, 0, 0);
        a = __builtin_amdgcn_mfma_f32_16x16x32_bf16(kah[u], qh[f], a, 0, 0, 0);
        s[u][f] = a;
      }
#pragma unroll
    for (int f = 0; f < 2; f++) {
      union { uint32 w[4]; bf16x8 v; } ph, pl;
#pragma unroll
      for (int u = 0; u < 2; u++) {
        const float p0 = __expf(s[u][f][0]);
        const float p1 = __expf(s[u][f][1]);
        const float p2 = __expf(s[u][f][2]);
        const float p3 = __expf(s[u][f][3]);
        lacc[f] += (p0 + p1) + (p2 + p3);
        unsigned int h01, h23;
        asm volatile("v_cvt_pk_bf16_f32 %0, %1, %2" : "=v"(h01) : "v"(p0), "v"(p1));
        asm volatile("v_cvt_pk_bf16_f32 %0, %1, %2" : "=v"(h23) : "v"(p2), "v"(p3));
        const float r0 = p0 - __uint_as_float(h01 << 16);
        const float r1 = p1 - __uint_as_float(h01 & 0xffff0000u);
        const float r2 = p2 - __uint_as_float(h23 << 16);
        const float r3 = p3 - __uint_as_float(h23 & 0xffff0000u);
        unsigned int l01, l23;
        asm volatile("v_cvt_pk_bf16_f32 %0, %1, %2" : "=v"(l01) : "v"(r0), "v"(r1));
        asm volatile("v_cvt_pk_bf16_f32 %0, %1, %2" : "=v"(l23) : "v"(r2), "v"(r3));
        ph.w[u * 2 + 0] = h01;
        ph.w[u * 2 + 1] = h23;
        pl.w[u * 2 + 0] = l01;
        pl.w[u * 2 + 1] = l23;
      }
#pragma unroll
      for (int df = 0; df < 2; df++) {
        oacc[df][f] = __builtin_amdgcn_mfma_f32_16x16x32_bf16(val[df], ph.v, oacc[df][f], 0, 0, 0);
        oacc[df][f] = __builtin_amdgcn_mfma_f32_16x16x32_bf16(vah[df], pl.v, oacc[df][f], 0, 0, 0);
        oacc[df][f] = __builtin_amdgcn_mfma_f32_16x16x32_bf16(vah[df], ph.v, oacc[df][f], 0, 0, 0);
      }
    }
  }

#pragma unroll
  for (int f = 0; f < 2; f++) {
    lacc[f] += __shfl_xor(lacc[f], 16, 64);
    lacc[f] += __shfl_xor(lacc[f], 32, 64);
  }
#pragma unroll
  for (int f = 0; f < 2; f++) {
    const float inv = 1.f / lacc[f];
    const int q = q0 + f * 16 + (lane & 15);
    uint32* op = o + (size_t)(b * S_ + q) * D_ + h * 32;
#pragma unroll
    for (int df = 0; df < 2; df++) {
      const int dbase = df * 16 + (lane >> 4) * 4;
#pragma unroll
      for (int r = 0; r < 4; r++)
        op[dbase + r] = pack_split(oacc[df][f][r] * inv);
    }
  }
}

// -------- parallel prefix-scan over 16384 masks (sequential semantics) ------
__global__ __launch_bounds__(256) void scan_kernel(const int* __restrict__ mask,
                                                   int* __restrict__ slots,
                                                   int* __restrict__ countp) {
  __shared__ int wtot[4];
  const int tid = threadIdx.x;
  const int lane = tid & 63, wid = tid >> 6;
  const int base = tid * 64;
  int s = 0;
#pragma unroll 8
  for (int i = 0; i < 64; i++) s += mask[base + i];
  int inc = s;
#pragma unroll
  for (int off = 1; off < 64; off <<= 1) {
    const int t = __shfl_up(inc, off, 64);
    if (lane >= off) inc += t;
  }
  if (lane == 63) wtot[wid] = inc;
  __syncthreads();
  int woff = 0;
#pragma unroll
  for (int w = 0; w < 4; w++) woff += (w < wid) ? wtot[w] : 0;
  const int total = wtot[0] + wtot[1] + wtot[2] + wtot[3];
  if (tid == 0) countp[0] = total < M_ ? total : M_;
  int run = woff + inc - s;
  for (int i = 0; i < 64; i++) {
    const int r = base + i;
    const int mk = mask[r];
    slots[r] = (mk && run < M_) ? run : -1;
    run += mk;
  }
}

// ---------------- scatter selected rows into memory -------------------------
__global__ __launch_bounds__(256) void scatter_kernel(const float* __restrict__ h,
                                                      const int* __restrict__ slots,
                                                      float* __restrict__ mem) {
  const int row  = blockIdx.x * 4 + (threadIdx.x >> 6);
  const int lane = threadIdx.x & 63;
  const int sl = slots[row];
  if (sl >= 0)
    *(float4*)(mem + (size_t)sl * D_ + lane * 4) =
        *(const float4*)(h + (size_t)row * D_ + lane * 4);
}

// ---------------- query norms (one wave per batch row) ----------------------
__global__ __launch_bounds__(256) void qnorm_kernel(const float* __restrict__ h,
                                                    float* __restrict__ qden) {
  const int b    = blockIdx.x * 4 + (threadIdx.x >> 6);
  const int lane = threadIdx.x & 63;
  const float4 c = *(const float4*)(h + (size_t)b * S_ * D_ + lane * 4);
  float sq = c.x * c.x + c.y * c.y + c.z * c.z + c.w * c.w;
  sq = wave_sum(sq);
  if (lane == 0) qden[b] = sqrtf(sq) + 1e-8f;
}

// ------- sims[b][r] for all 32 b: one wave per memory row r -----------------
__global__ __launch_bounds__(256) void sims_kernel(const float* __restrict__ h,
                                                   const float* __restrict__ mem,
                                                   const float* __restrict__ qden,
                                                   const int* __restrict__ countp,
                                                   float* __restrict__ sims) {
  __shared__ float cls[B_ * D_];
  __shared__ float qd[B_];
  const int tid = threadIdx.x;
  const int lane = tid & 63, wid = tid >> 6;
  for (int i = tid; i < B_ * D_ / 4; i += 256) {
    const int flat = i * 4;
    const int b = flat >> 8, d = flat & 255;
    *(float4*)&cls[flat] = *(const float4*)(h + (size_t)b * S_ * D_ + d);
  }
  if (tid < B_) qd[tid] = qden[tid];
  __syncthreads();
  const int count = countp[0];
  const int r = blockIdx.x * 4 + wid;
  const float4 m4 = *(const float4*)(mem + (size_t)r * D_ + lane * 4);
  float sq = m4.x * m4.x + m4.y * m4.y + m4.z * m4.z + m4.w * m4.w;
  sq = wave_sum(sq);
  const float rn = sqrtf(sq) + 1e-8f;
  if (r < count) {
    for (int b = 0; b < B_; b++) {
      const float4 c4 = *(const float4*)&cls[b * D_ + lane * 4];
      float dt = m4.x * c4.x + m4.y * c4.y + m4.z * c4.z + m4.w * c4.w;
      dt = wave_sum(dt);
      if (lane == 0) sims[b * M_ + r] = dt / (qd[b] * rn);
    }
  } else if (lane == 0) {
    for (int b = 0; b < B_; b++) sims[b * M_ + r] = -1e9f;
  }
}

// ---------------- per-batch: top-4 (wave-parallel argmax), mix, classifier --
__global__ __launch_bounds__(256) void topk_mix(const float* __restrict__ h,
                                                const float* __restrict__ mem,
                                                const float* __restrict__ simsg,
                                                const int* __restrict__ countp,
                                                const float* __restrict__ Wc,
                                                const float* __restrict__ bc,
                                                float* __restrict__ out) {
  __shared__ float sims[M_];
  __shared__ float cls[D_];
  __shared__ float wv4[4];
  __shared__ int   wi4[4];
  __shared__ float aug[D_];
  __shared__ float tv[4];
  __shared__ int   tix[4];

  const int b = blockIdx.x, tid = threadIdx.x;
  const int lane = tid & 63, wid = tid >> 6;
  const int count = countp[0];

  for (int i = tid; i < M_; i += 256) sims[i] = simsg[b * M_ + i];
  cls[tid] = h[(size_t)b * S_ * D_ + tid];
  __syncthreads();

  for (int k = 0; k < 4; k++) {
    float bv = -INFINITY; int bi = 1 << 30;
#pragma unroll
    for (int rr = 0; rr < M_ / 256; rr++) {
      const int r = tid + rr * 256;
      const float v = sims[r];
      if (v > bv || (v == bv && r < bi)) { bv = v; bi = r; }
    }
#pragma unroll
    for (int off = 1; off < 64; off <<= 1) {
      const float ov = __shfl_xor(bv, off, 64);
      const int   oi = __shfl_xor(bi, off, 64);
      if (ov > bv || (ov == bv && oi < bi)) { bv = ov; bi = oi; }
    }
    if (lane == 0) { wv4[wid] = bv; wi4[wid] = bi; }
    __syncthreads();
    if (tid == 0) {
      float bb = wv4[0]; int bbi = wi4[0];
#pragma unroll
      for (int i = 1; i < 4; i++)
        if (wv4[i] > bb || (wv4[i] == bb && wi4[i] < bbi)) { bb = wv4[i]; bbi = wi4[i]; }
      tv[k] = bb; tix[k] = bbi; sims[bbi] = -INFINITY;
    }
    __syncthreads();
  }

  float w[4];
  {
    const float mx = tv[0];
    float ws = 0.f;
#pragma unroll
    for (int k = 0; k < 4; k++) { w[k] = expf(tv[k] - mx); ws += w[k]; }
    const float inv = 1.f / ws;
#pragma unroll
    for (int k = 0; k < 4; k++) w[k] *= inv;
  }

  {
    float mv = 0.f;
    if (count > 0) {
#pragma unroll
      for (int k = 0; k < 4; k++) mv = fmaf(w[k], mem[(size_t)tix[k] * D_ + tid], mv);
    }
    aug[tid] = cls[tid] + mv;
  }
  __syncthreads();

  const float4 a4 = *(const float4*)&aug[lane * 4];
  for (int c = wid; c < NC_; c += 4) {
    const float4 wc = *(const float4*)(Wc + (size_t)c * D_ + lane * 4);
    float dt = a4.x * wc.x + a4.y * wc.y + a4.z * wc.z + a4.w * wc.w;
    dt = wave_sum(dt);
    if (lane == 0) out[b * NC_ + c] = dt + bc[c];
  }
}

// ---------------- launcher ---------------------------------------------------
extern "C" void kernel_launch(void* const* d_in, const int* in_sizes, int n_in,
                              void* d_out, int out_size, void* d_ws, size_t ws_size,
                              hipStream_t stream) {
  const int*   ids  = (const int*)d_in[0];
  const float* tok  = (const float*)d_in[1];
  const float* pos  = (const float*)d_in[2];
  const float* Wqkv = (const float*)d_in[3];
  const float* bqkv = (const float*)d_in[4];
  const float* Wo   = (const float*)d_in[5];
  const float* bo   = (const float*)d_in[6];
  const float* ln1g = (const float*)d_in[7];
  const float* ln1b = (const float*)d_in[8];
  const float* W1   = (const float*)d_in[9];
  const float* b1   = (const float*)d_in[10];
  const float* W2   = (const float*)d_in[11];
  const float* b2   = (const float*)d_in[12];
  const float* ln2g = (const float*)d_in[13];
  const float* ln2b = (const float*)d_in[14];
  const float* Wg1  = (const float*)d_in[15];
  const float* bg1  = (const float*)d_in[16];
  const float* Wg2  = (const float*)d_in[17];
  const float* bg2  = (const float*)d_in[18];
  const float* Wc   = (const float*)d_in[19];
  const float* bc   = (const float*)d_in[20];
  float* out = (float*)d_out;

  // workspace (all 4-byte words)
  float*  xA    = (float*)d_ws;                    // ROWS*D
  float*  xB    = xA  + (size_t)ROWS * D_;
  uint32* xAp   = (uint32*)(xB + (size_t)ROWS * D_);
  uint32* xBp   = xAp + (size_t)ROWS * D_;
  uint32* obp   = xBp + (size_t)ROWS * D_;
  uint32* bigp  = obp + (size_t)ROWS * D_;         // ROWS*FF (QKV 768 / FF1 1024)
  uint32* Wqkvp = bigp + (size_t)ROWS * FF_;       // L*768*256
  uint32* Wop   = Wqkvp + (size_t)L_ * 768 * 256;  // L*256*256
  uint32* W1p   = Wop   + (size_t)L_ * 256 * 256;  // L*1024*256
  uint32* W2p   = W1p   + (size_t)L_ * 1024 * 256; // L*256*1024
  uint32* Wg1p  = W2p   + (size_t)L_ * 256 * 1024; // 256*256
  float*  mem   = (float*)(Wg1p + 256 * 256);
  float*  qden  = mem + (size_t)M_ * D_;
  float*  sims  = qden + 64;
  int*    mask  = (int*)(sims + (size_t)B_ * M_);
  int*    slots = mask + ROWS;
  int*    cnt   = slots + ROWS;

  // pack weights once
  pack_f32<<<(L_ * 768 * 256 / 4 + 255) / 256, 256, 0, stream>>>(Wqkv, Wqkvp, L_ * 768 * 256 / 4);
  pack_f32<<<(L_ * 256 * 256 / 4 + 255) / 256, 256, 0, stream>>>(Wo, Wop, L_ * 256 * 256 / 4);
  pack_f32<<<(L_ * 1024 * 256 / 4 + 255) / 256, 256, 0, stream>>>(W1, W1p, L_ * 1024 * 256 / 4);
  pack_f32<<<(L_ * 256 * 1024 / 4 + 255) / 256, 256, 0, stream>>>(W2, W2p, L_ * 256 * 1024 / 4);
  pack_f32<<<(256 * 256 / 4 + 255) / 256, 256, 0, stream>>>(Wg1, Wg1p, 256 * 256 / 4);

  emb_kernel<<<ROWS / 4, 256, 0, stream>>>(ids, tok, pos, xA, xAp);

  for (int l = 0; l < L_; l++) {
    gemm_mfma<0, 1><<<768, 256, 0, stream>>>(
        xAp, Wqkvp + (size_t)l * 768 * 256, bqkv + l * 768, nullptr, bigp, 256, 768, 6);
    attn_mfma<<<B_ * H_, 1024, 0, stream>>>(bigp, obp);
    // Wo GEMM fused with residual(xA) + LN1 -> xB (fp32 + packed)
    gemm_ln<0><<<ROWS / 64, 512, 0, stream>>>(
        obp, Wop + (size_t)l * 256 * 256, bo + l * 256, xA,
        ln1g + l * 256, ln1b + l * 256, nullptr, nullptr, xB, xBp, nullptr, 256);
    gemm_mfma<1, 1><<<1024, 256, 0, stream>>>(
        xBp, W1p + (size_t)l * 1024 * 256, b1 + l * 1024, nullptr, bigp, 256, 1024, 8);
    // W2 GEMM fused with residual(xB) + LN2 -> xA (fp32 + packed)
    gemm_ln<0><<<ROWS / 64, 512, 0, stream>>>(
        bigp, W2p + (size_t)l * 256 * 1024, b2 + l * 256, xB,
        ln2g + l * 256, ln2b + l * 256, nullptr, nullptr, xA, xAp, nullptr, 1024);
  }

  // gate MLP fused: mask[row] = (relu(h@Wg1^T+bg1) . Wg2 + bg2) > 0
  gemm_ln<1><<<ROWS / 64, 512, 0, stream>>>(
      xAp, Wg1p, bg1, nullptr, nullptr, nullptr, Wg2, bg2, nullptr, nullptr, mask, 256);
  scan_kernel<<<1, 256, 0, stream>>>(mask, slots, cnt);
  (void)hipMemsetAsync(mem, 0, (size_t)M_ * D_ * sizeof(float), stream);
  scatter_kernel<<<ROWS / 4, 256, 0, stream>>>(xA, slots, mem);

  qnorm_kernel<<<B_ / 4, 256, 0, stream>>>(xA, qden);
  sims_kernel<<<M_ / 4, 256, 0, stream>>>(xA, mem, qden, cnt, sims);
  topk_mix<<<B_, 256, 0, stream>>>(xA, mem, sims, cnt, Wc, bc, out);
}